// Round 4
// baseline (913.477 us; speedup 1.0000x reference)
//
#include <hip/hip_runtime.h>
#include <hip/hip_bf16.h>

#define N_NODES 100000
#define N_EDGES 600000
#define HD 128
#define NBC 384
#define LST 136  // LDS row stride (bf16 elems): 128 + 8 pad (272B) breaks power-of-2 conflicts
#define SCAN_B 98  // ceil(N_NODES/1024)

typedef __attribute__((ext_vector_type(8))) short s8v;
typedef __attribute__((ext_vector_type(4))) float f4v;
typedef __hip_bfloat16 bf16;

static __device__ __forceinline__ float bf2f(bf16 v) { return __bfloat162float(v); }
static __device__ __forceinline__ bf16 f2bf(float v) { return __float2bfloat16(v); }

// ================= dtype detection =================
__global__ void k_detect(const unsigned short* __restrict__ wraw,
                         const int* __restrict__ eraw, int* __restrict__ flags) {
    if (threadIdx.x == 0 && blockIdx.x == 0) {
        int fp32 = 0;
        for (int i = 0; i < 1024; i++) {
            unsigned int u = ((unsigned int)wraw[i]) << 16;
            float f = fabsf(__uint_as_float(u));
            if (!(f <= 1e4f)) fp32 = 1;  // catches huge AND NaN
        }
        int i64 = (eraw[1] == 0 && eraw[3] == 0 && eraw[5] == 0 && eraw[7] == 0) ? 1 : 0;
        flags[0] = fp32;
        flags[1] = i64;
    }
}

// ================= canonical conversion (all float inputs -> bf16) =================
#define B_CF 5860
#define C1 (B_CF)
#define C2 (C1 + 391)
#define C3 (C2 + 12500)
#define C4 (C3 + 2)
#define C5 (C4 + 24)
#define C6 (C5 + 1)
#define C7 (C6 + 128)
#define C8 (C7 + 1)
#define C9 (C8 + 192)
#define C10 (C9 + 1)
__global__ void k_cvt_all(const int* __restrict__ flags,
                          const void* s0, const void* s1, const void* s2, const void* s3,
                          const void* s4, const void* s5, const void* s6, const void* s7,
                          const void* s8, const void* s9,
                          bf16* d0, bf16* d1, bf16* d2, bf16* d3, bf16* d4,
                          bf16* d5, bf16* d6, bf16* d7, bf16* d8, bf16* d9) {
    int b = blockIdx.x;
    const void* src; bf16* dst; int n, lb;
    if (b < C1)       { src = s0; dst = d0; n = 1500000; lb = b; }
    else if (b < C2)  { src = s1; dst = d1; n = 100000;  lb = b - C1; }
    else if (b < C3)  { src = s2; dst = d2; n = 3200000; lb = b - C2; }
    else if (b < C4)  { src = s3; dst = d3; n = 384;     lb = b - C3; }
    else if (b < C5)  { src = s4; dst = d4; n = 6144;    lb = b - C4; }
    else if (b < C6)  { src = s5; dst = d5; n = 128;     lb = b - C5; }
    else if (b < C7)  { src = s6; dst = d6; n = 32768;   lb = b - C6; }
    else if (b < C8)  { src = s7; dst = d7; n = 128;     lb = b - C7; }
    else if (b < C9)  { src = s8; dst = d8; n = 49152;   lb = b - C8; }
    else              { src = s9; dst = d9; n = 128;     lb = b - C9; }
    int i = lb * 256 + threadIdx.x;
    if (i < n) {
        if (flags[0]) dst[i] = f2bf(((const float*)src)[i]);
        else          dst[i] = ((const bf16*)src)[i];
    }
}

#define B_E 4688
__global__ void k_cvt_ints(const int* __restrict__ flags, const int* __restrict__ e,
                           const int* __restrict__ cc, int* __restrict__ ec,
                           int* __restrict__ ccc) {
    int i64 = flags[1];
    int b = blockIdx.x;
    if (b < B_E) {
        int i = b * 256 + threadIdx.x;
        if (i < 2 * N_EDGES) ec[i] = i64 ? e[2 * i] : e[i];
    } else {
        int i = (b - B_E) * 256 + threadIdx.x;
        if (i < N_NODES) ccc[i] = i64 ? cc[2 * i] : cc[i];
    }
}

// ================= weight transpose: W[k][n] -> Wt[n][k] =================
__global__ void k_prep_w(const bf16* __restrict__ Wm, const bf16* __restrict__ Wu,
                         bf16* __restrict__ Wmt, bf16* __restrict__ Wut) {
    int i = blockIdx.x * 256 + threadIdx.x;
    if (i < 128 * 256) {
        int n = i >> 8, k = i & 255;
        Wmt[i] = Wm[k * 128 + n];
    } else {
        int j = i - 128 * 256;
        if (j < 128 * 384) {
            int n = j / 384, k = j - n * 384;
            Wut[j] = Wu[k * 128 + n];
        }
    }
}

// ================= encoder =================
__global__ void k_encoder(const bf16* __restrict__ cf, const bf16* __restrict__ slf,
                          const bf16* __restrict__ z, const bf16* __restrict__ W,
                          const bf16* __restrict__ b, float* __restrict__ x,
                          bf16* __restrict__ xb) {
    __shared__ float in[2][48];
    int half = threadIdx.x >> 7, t = threadIdx.x & 127;
    int node = blockIdx.x * 2 + half;
    if (t < 48) {
        float v;
        if (t < 15) v = bf2f(cf[node * 15 + t]);
        else if (t == 15) v = bf2f(slf[node]);
        else v = bf2f(z[node * 32 + (t - 16)]);
        in[half][t] = v;
    }
    __syncthreads();
    float acc = bf2f(b[t]);
#pragma unroll 8
    for (int k = 0; k < 48; k++) acc += in[half][k] * bf2f(W[k * 128 + t]);
    size_t idx = (size_t)node * HD + t;
    x[idx] = acc;
    xb[idx] = f2bf(acc);
}

// ================= CSR build =================
__global__ void k_count_edges(const int* __restrict__ e, int* __restrict__ deg) {
    int i = blockIdx.x * 256 + threadIdx.x;
    if (i < N_EDGES) atomicAdd(&deg[e[N_EDGES + i]], 1);
}
__global__ void k_count_nodes(const int* __restrict__ cc, int* __restrict__ ccount) {
    int i = blockIdx.x * 256 + threadIdx.x;
    if (i < N_NODES) atomicAdd(&ccount[cc[i]], 1);
}

__global__ void k_scan_a(const int* __restrict__ deg, int* __restrict__ rowptr,
                         int* __restrict__ bsum) {
    __shared__ int sd[1024];
    int t = threadIdx.x;
    int i = blockIdx.x * 1024 + t;
    int v = (i < N_NODES) ? deg[i] : 0;
    sd[t] = v;
    __syncthreads();
#pragma unroll
    for (int off = 1; off < 1024; off <<= 1) {
        int u = (t >= off) ? sd[t - off] : 0;
        __syncthreads();
        sd[t] += u;
        __syncthreads();
    }
    if (i < N_NODES) rowptr[i] = sd[t] - v;
    if (t == 1023) bsum[blockIdx.x] = sd[t];
}
__global__ void k_scan_b(const int* __restrict__ bsum, int* __restrict__ boff,
                         int* __restrict__ rowptr) {
    __shared__ int sd[128];
    int t = threadIdx.x;
    int v = (t < SCAN_B) ? bsum[t] : 0;
    sd[t] = v;
    __syncthreads();
#pragma unroll
    for (int off = 1; off < 128; off <<= 1) {
        int u = (t >= off) ? sd[t - off] : 0;
        __syncthreads();
        sd[t] += u;
        __syncthreads();
    }
    if (t < SCAN_B) boff[t] = sd[t] - v;
    if (t == 0) rowptr[N_NODES] = N_EDGES;
}
__global__ void k_scan_c(int* __restrict__ rowptr, int* __restrict__ cursor,
                         const int* __restrict__ boff) {
    int i = blockIdx.x * 1024 + threadIdx.x;
    if (i < N_NODES) {
        int r = rowptr[i] + boff[blockIdx.x];
        rowptr[i] = r;
        cursor[i] = r;
    }
}

__global__ void k_scan_clusters(const int* __restrict__ ccount, int* __restrict__ coff,
                                int* __restrict__ ccur) {
    __shared__ int sd[512];
    int t = threadIdx.x;
    sd[t] = (t < NBC) ? ccount[t] : 0;
    __syncthreads();
    for (int off = 1; off < 512; off <<= 1) {
        int v = (t >= off) ? sd[t - off] : 0;
        __syncthreads();
        sd[t] += v;
        __syncthreads();
    }
    if (t < NBC) {
        int ex = (t == 0) ? 0 : sd[t - 1];
        coff[t] = ex;
        ccur[t] = ex;
        if (t == NBC - 1) coff[NBC] = sd[t];
    }
}

__global__ void k_fill_edges(const int* __restrict__ e, int* __restrict__ cursor,
                             int* __restrict__ colx) {
    int i = blockIdx.x * 256 + threadIdx.x;
    if (i < N_EDGES) {
        int d = e[N_EDGES + i];
        int p = atomicAdd(&cursor[d], 1);
        colx[p] = e[i];
    }
}
__global__ void k_fill_nodes(const int* __restrict__ cc, int* __restrict__ ccur,
                             int* __restrict__ cnodes) {
    int i = blockIdx.x * 256 + threadIdx.x;
    if (i < N_NODES) {
        int p = atomicAdd(&ccur[cc[i]], 1);
        cnodes[p] = i;
    }
}

// ================= per-layer: mean of x[src] over incoming edges =================
__global__ void k_aggregate(const bf16* __restrict__ xb, const int* __restrict__ rowptr,
                            const int* __restrict__ colx, bf16* __restrict__ mb) {
    int wave = threadIdx.x >> 6, lane = threadIdx.x & 63;
    int node = blockIdx.x * 4 + wave;
    if (node >= N_NODES) return;
    int lo = rowptr[node], hi = rowptr[node + 1];
    float a0 = 0.f, a1 = 0.f;
    int j = lo;
    // 2-wide unroll: two independent gathers in flight
    while (j + 2 <= hi) {
        int s0 = colx[j], s1 = colx[j + 1];
        __hip_bfloat162 v0 = *((const __hip_bfloat162*)(xb + (size_t)s0 * HD) + lane);
        __hip_bfloat162 v1 = *((const __hip_bfloat162*)(xb + (size_t)s1 * HD) + lane);
        a0 += bf2f(v0.x) + bf2f(v1.x);
        a1 += bf2f(v0.y) + bf2f(v1.y);
        j += 2;
    }
    if (j < hi) {
        int s0 = colx[j];
        __hip_bfloat162 v0 = *((const __hip_bfloat162*)(xb + (size_t)s0 * HD) + lane);
        a0 += bf2f(v0.x);
        a1 += bf2f(v0.y);
    }
    int d = hi - lo;
    float inv = 1.0f / (float)(d > 1 ? d : 1);
    __hip_bfloat162 o;
    o.x = f2bf(a0 * inv);
    o.y = f2bf(a1 * inv);
    *((__hip_bfloat162*)(mb + (size_t)node * HD) + lane) = o;
}

// ================= per-layer: cluster pooling =================
__global__ void k_pool_partial(const float* __restrict__ x, const int* __restrict__ coff,
                               const int* __restrict__ cnodes, float* __restrict__ pf) {
    int cl = blockIdx.x >> 2, seg = blockIdx.x & 3;
    int lo = coff[cl], hi = coff[cl + 1];
    int cnt = hi - lo;
    int per = (cnt + 3) >> 2;
    int s0 = lo + seg * per;
    int s1 = min(s0 + per, hi);
    int col = threadIdx.x & 127, half = threadIdx.x >> 7;
    float a = 0.f;
    for (int i = s0 + half; i < s1; i += 2) a += x[(size_t)cnodes[i] * HD + col];
    __shared__ float red[256];
    red[threadIdx.x] = a;
    __syncthreads();
    if (half == 0) {
        float s = red[col] + red[col + 128];
        atomicAdd(&pf[cl * HD + col], s);
    }
}
__global__ void k_pool_final(const float* __restrict__ pf, const int* __restrict__ ccount,
                             const bf16* __restrict__ tr, bf16* __restrict__ pooled) {
    int i = blockIdx.x * 256 + threadIdx.x;
    int cl = i >> 7;
    int c = ccount[cl];
    float v = pf[i] / (float)(c > 1 ? c : 1) * bf2f(tr[cl]);
    pooled[i] = f2bf(v);
}

// ================= per-layer fused update =================
// A-fragments loaded DIRECTLY from global (L1/L2-hot; rows block-exclusive so LDS
// staging added no cross-block reuse). Only Gs (17.4KB) remains in LDS -> ~7 blocks/CU
// vs 3 with full staging. OOB rows handled branch-free by clamping the row index
// (garbage rows computed but never stored). xb ping-pongs across layers (no race).
// last!=0: write d_out (dtype per flags[0]) instead of x/xb.
__global__ __launch_bounds__(256) void k_update(
    const bf16* __restrict__ xb, const bf16* __restrict__ mb, const bf16* __restrict__ pooled,
    const bf16* __restrict__ Wmt, const bf16* __restrict__ Wut,
    const bf16* __restrict__ bm, const bf16* __restrict__ bu,
    const int* __restrict__ cc, const int* __restrict__ deg,
    float* __restrict__ x, bf16* __restrict__ xbo,
    const int* __restrict__ flags, void* __restrict__ out, int last) {
    __shared__ __align__(16) short Gs[64 * LST];
    int tid = threadIdx.x;
    int r0 = blockIdx.x * 64;
    int wave = tid >> 6, lane = tid & 63, quad = lane >> 4, nidx = lane & 15;
    int colbase = wave * 32;

    // clamped A-row index per rt (branch-free OOB)
    int arow[4];
#pragma unroll
    for (int rt = 0; rt < 4; rt++) {
        int gr = r0 + rt * 16 + nidx;
        arow[rt] = (gr < N_NODES) ? gr : (N_NODES - 1);
    }

    f4v acc[4][2];
#pragma unroll
    for (int rt = 0; rt < 4; rt++)
#pragma unroll
        for (int ct = 0; ct < 2; ct++) acc[rt][ct] = (f4v){0.f, 0.f, 0.f, 0.f};

    // phase 1: [x | m] @ Wm  (A direct from global)
#pragma unroll
    for (int s = 0; s < 8; s++) {
        int k0 = s * 32;
        const short* Asrc = (s < 4) ? (const short*)xb : (const short*)mb;
        int kk = (s < 4) ? k0 : (k0 - 128);
        s8v afr[4];
#pragma unroll
        for (int rt = 0; rt < 4; rt++)
            afr[rt] = *(const s8v*)(Asrc + (size_t)arow[rt] * HD + kk + quad * 8);
#pragma unroll
        for (int ct = 0; ct < 2; ct++) {
            s8v bfr = *(const s8v*)((const short*)Wmt + (colbase + ct * 16 + nidx) * 256 + k0 + quad * 8);
#pragma unroll
            for (int rt = 0; rt < 4; rt++)
                acc[rt][ct] = __builtin_amdgcn_mfma_f32_16x16x32_bf16(afr[rt], bfr, acc[rt][ct], 0, 0, 0);
        }
    }
    // epilogue 1 -> Gs (bf16, A-layout for phase 2)
#pragma unroll
    for (int ct = 0; ct < 2; ct++) {
        int col = colbase + ct * 16 + nidx;
        float bmv = bf2f(bm[col]);
#pragma unroll
        for (int rt = 0; rt < 4; rt++) {
#pragma unroll
            for (int r = 0; r < 4; r++) {
                int lrow = rt * 16 + quad * 4 + r;
                int gr = r0 + lrow;
                int d = deg[(gr < N_NODES) ? gr : (N_NODES - 1)];
                float v = (d > 0) ? (acc[rt][ct][r] + bmv) : 0.f;
                bf16 h = f2bf(v);
                Gs[lrow * LST + col] = *(short*)&h;
            }
        }
    }
    __syncthreads();

    // phase 2: [x | aggr | pooled[cc]] @ Wu
    int cci[4];
#pragma unroll
    for (int rt = 0; rt < 4; rt++) cci[rt] = cc[arow[rt]];
#pragma unroll
    for (int rt = 0; rt < 4; rt++)
#pragma unroll
        for (int ct = 0; ct < 2; ct++) acc[rt][ct] = (f4v){0.f, 0.f, 0.f, 0.f};
#pragma unroll
    for (int s = 0; s < 12; s++) {
        int k0 = s * 32;
        s8v afr[4];
        if (s < 4) {
#pragma unroll
            for (int rt = 0; rt < 4; rt++)
                afr[rt] = *(const s8v*)((const short*)xb + (size_t)arow[rt] * HD + k0 + quad * 8);
        } else if (s < 8) {
            int kk = k0 - 128;
#pragma unroll
            for (int rt = 0; rt < 4; rt++)
                afr[rt] = *(const s8v*)(Gs + (rt * 16 + nidx) * LST + kk + quad * 8);
        } else {
            int kk = k0 - 256;
#pragma unroll
            for (int rt = 0; rt < 4; rt++)
                afr[rt] = *(const s8v*)((const short*)pooled + (size_t)cci[rt] * HD + kk + quad * 8);
        }
#pragma unroll
        for (int ct = 0; ct < 2; ct++) {
            s8v bfr = *(const s8v*)((const short*)Wut + (colbase + ct * 16 + nidx) * 384 + k0 + quad * 8);
#pragma unroll
            for (int rt = 0; rt < 4; rt++)
                acc[rt][ct] = __builtin_amdgcn_mfma_f32_16x16x32_bf16(afr[rt], bfr, acc[rt][ct], 0, 0, 0);
        }
    }
    // epilogue 2: bias, leaky-relu, residual; last layer writes d_out directly
    int fp32out = flags[0];
#pragma unroll
    for (int ct = 0; ct < 2; ct++) {
        int col = colbase + ct * 16 + nidx;
        float buv = bf2f(bu[col]);
#pragma unroll
        for (int rt = 0; rt < 4; rt++) {
#pragma unroll
            for (int r = 0; r < 4; r++) {
                int lrow = rt * 16 + quad * 4 + r;
                int gr = r0 + lrow;
                if (gr < N_NODES) {
                    float v = acc[rt][ct][r] + buv;
                    v = (v > 0.f) ? v : 0.01f * v;
                    size_t idx = (size_t)gr * HD + col;
                    float nv = x[idx] + v;
                    if (last) {
                        if (fp32out) ((float*)out)[idx] = nv;
                        else ((bf16*)out)[idx] = f2bf(nv);
                    } else {
                        x[idx] = nv;
                        xbo[idx] = f2bf(nv);
                    }
                }
            }
        }
    }
}

extern "C" void kernel_launch(void* const* d_in, const int* in_sizes, int n_in,
                              void* d_out, int out_size, void* d_ws, size_t ws_size,
                              hipStream_t stream) {
    const void* cf_r = d_in[0];
    const void* slf_r = d_in[1];
    const void* z_r = d_in[2];
    const void* tr_r = d_in[3];
    const void* Wenc_r = d_in[4];
    const void* benc_r = d_in[5];
    const void* Wm_r = d_in[6];
    const void* bm_r = d_in[7];
    const void* Wu_r = d_in[8];
    const void* bu_r = d_in[9];
    const int* e_r = (const int*)d_in[10];
    const int* cc_r = (const int*)d_in[11];

    char* w = (char*)d_ws;
    auto alloc = [&](size_t bytes) -> char* {
        char* p = w;
        w += (bytes + 63) & ~(size_t)63;
        return p;
    };
    float* x = (float*)alloc((size_t)N_NODES * HD * 4);
    bf16* xb0 = (bf16*)alloc((size_t)N_NODES * HD * 2);
    bf16* xb1 = (bf16*)alloc((size_t)N_NODES * HD * 2);
    bf16* mb = (bf16*)alloc((size_t)N_NODES * HD * 2);
    bf16* Wmt = (bf16*)alloc(128 * 256 * 2);
    bf16* Wut = (bf16*)alloc(128 * 384 * 2);
    float* pooledf = (float*)alloc(NBC * HD * 4);
    bf16* pooled = (bf16*)alloc(NBC * HD * 2);
    int* deg = (int*)alloc(N_NODES * 4);
    int* rowptr = (int*)alloc((N_NODES + 1) * 4);
    int* cursor = (int*)alloc(N_NODES * 4);
    int* colx = (int*)alloc(N_EDGES * 4);
    int* ccount = (int*)alloc(NBC * 4);
    int* coff = (int*)alloc((NBC + 1) * 4);
    int* ccur = (int*)alloc(NBC * 4);
    int* cnodes = (int*)alloc(N_NODES * 4);
    int* flags = (int*)alloc(64);
    int* bsum = (int*)alloc(SCAN_B * 4);
    int* boff = (int*)alloc(SCAN_B * 4);
    bf16* cfc = (bf16*)alloc(1500000 * 2);
    bf16* slfc = (bf16*)alloc(100000 * 2);
    bf16* zc = (bf16*)alloc(3200000 * 2);
    bf16* trc = (bf16*)alloc(384 * 2);
    bf16* Wencc = (bf16*)alloc(6144 * 2);
    bf16* bencc = (bf16*)alloc(128 * 2);
    bf16* Wmc = (bf16*)alloc(32768 * 2);
    bf16* bmc = (bf16*)alloc(128 * 2);
    bf16* Wuc = (bf16*)alloc(49152 * 2);
    bf16* buc = (bf16*)alloc(128 * 2);
    int* ec = (int*)alloc(2 * N_EDGES * 4);
    int* ccc = (int*)alloc(N_NODES * 4);

    // dtype detection + canonical conversion
    k_detect<<<1, 64, 0, stream>>>((const unsigned short*)Wenc_r, e_r, flags);
    k_cvt_all<<<C10, 256, 0, stream>>>(flags, cf_r, slf_r, z_r, tr_r, Wenc_r, benc_r,
                                       Wm_r, bm_r, Wu_r, bu_r,
                                       cfc, slfc, zc, trc, Wencc, bencc, Wmc, bmc, Wuc, buc);
    k_cvt_ints<<<B_E + 391, 256, 0, stream>>>(flags, e_r, cc_r, ec, ccc);

    // weight prep + encoder
    k_prep_w<<<(128 * 256 + 128 * 384) / 256, 256, 0, stream>>>(Wmc, Wuc, Wmt, Wut);
    k_encoder<<<N_NODES / 2, 256, 0, stream>>>(cfc, slfc, zc, Wencc, bencc, x, xb0);

    // CSR build
    hipMemsetAsync(deg, 0, (size_t)N_NODES * 4, stream);
    hipMemsetAsync(ccount, 0, (size_t)NBC * 4, stream);
    k_count_edges<<<(N_EDGES + 255) / 256, 256, 0, stream>>>(ec, deg);
    k_count_nodes<<<(N_NODES + 255) / 256, 256, 0, stream>>>(ccc, ccount);
    k_scan_a<<<SCAN_B, 1024, 0, stream>>>(deg, rowptr, bsum);
    k_scan_b<<<1, 128, 0, stream>>>(bsum, boff, rowptr);
    k_scan_c<<<SCAN_B, 1024, 0, stream>>>(rowptr, cursor, boff);
    k_scan_clusters<<<1, 512, 0, stream>>>(ccount, coff, ccur);
    k_fill_edges<<<(N_EDGES + 255) / 256, 256, 0, stream>>>(ec, cursor, colx);
    k_fill_nodes<<<(N_NODES + 255) / 256, 256, 0, stream>>>(ccc, ccur, cnodes);

    bf16* xbufs[2] = {xb0, xb1};
    for (int layer = 0; layer < 3; layer++) {
        bf16* xbi = xbufs[layer & 1];
        bf16* xbo = xbufs[(layer + 1) & 1];
        int last = (layer == 2);
        hipMemsetAsync(pooledf, 0, (size_t)NBC * HD * 4, stream);
        k_aggregate<<<N_NODES / 4, 256, 0, stream>>>(xbi, rowptr, colx, mb);
        k_pool_partial<<<NBC * 4, 256, 0, stream>>>(x, coff, cnodes, pooledf);
        k_pool_final<<<NBC * HD / 256, 256, 0, stream>>>(pooledf, ccount, trc, pooled);
        k_update<<<(N_NODES + 63) / 64, 256, 0, stream>>>(xbi, mb, pooled, Wmt, Wut,
                                                          bmc, buc, ccc, deg, x, xbo,
                                                          flags, d_out, last);
    }
}

// Round 5
// 839.140 us; speedup vs baseline: 1.0886x; 1.0886x over previous
//
#include <hip/hip_runtime.h>
#include <hip/hip_bf16.h>

#define N_NODES 100000
#define N_EDGES 600000
#define HD 128
#define NBC 384
#define SCAN_B 98   // ceil(N_NODES/1024)
#define MAXFIX 4096 // cap on deg-0 fixup list (E[count]~250 for Poisson(6))

typedef __attribute__((ext_vector_type(8))) short s8v;
typedef __attribute__((ext_vector_type(4))) short s4v;
typedef __attribute__((ext_vector_type(4))) float f4v;
typedef __hip_bfloat16 bf16;

static __device__ __forceinline__ float bf2f(bf16 v) { return __bfloat162float(v); }
static __device__ __forceinline__ bf16 f2bf(float v) { return __float2bfloat16(v); }

// ================= dtype detection =================
__global__ void k_detect(const unsigned short* __restrict__ wraw,
                         const int* __restrict__ eraw, int* __restrict__ flags) {
    if (threadIdx.x == 0 && blockIdx.x == 0) {
        int fp32 = 0;
        for (int i = 0; i < 1024; i++) {
            unsigned int u = ((unsigned int)wraw[i]) << 16;
            float f = fabsf(__uint_as_float(u));
            if (!(f <= 1e4f)) fp32 = 1;  // catches huge AND NaN
        }
        int i64 = (eraw[1] == 0 && eraw[3] == 0 && eraw[5] == 0 && eraw[7] == 0) ? 1 : 0;
        flags[0] = fp32;
        flags[1] = i64;
    }
}

// ================= canonical conversion (all float inputs -> bf16) =================
#define B_CF 5860
#define C1 (B_CF)
#define C2 (C1 + 391)
#define C3 (C2 + 12500)
#define C4 (C3 + 2)
#define C5 (C4 + 24)
#define C6 (C5 + 1)
#define C7 (C6 + 128)
#define C8 (C7 + 1)
#define C9 (C8 + 192)
#define C10 (C9 + 1)
__global__ void k_cvt_all(const int* __restrict__ flags,
                          const void* s0, const void* s1, const void* s2, const void* s3,
                          const void* s4, const void* s5, const void* s6, const void* s7,
                          const void* s8, const void* s9,
                          bf16* d0, bf16* d1, bf16* d2, bf16* d3, bf16* d4,
                          bf16* d5, bf16* d6, bf16* d7, bf16* d8, bf16* d9) {
    int b = blockIdx.x;
    const void* src; bf16* dst; int n, lb;
    if (b < C1)       { src = s0; dst = d0; n = 1500000; lb = b; }
    else if (b < C2)  { src = s1; dst = d1; n = 100000;  lb = b - C1; }
    else if (b < C3)  { src = s2; dst = d2; n = 3200000; lb = b - C2; }
    else if (b < C4)  { src = s3; dst = d3; n = 384;     lb = b - C3; }
    else if (b < C5)  { src = s4; dst = d4; n = 6144;    lb = b - C4; }
    else if (b < C6)  { src = s5; dst = d5; n = 128;     lb = b - C5; }
    else if (b < C7)  { src = s6; dst = d6; n = 32768;   lb = b - C6; }
    else if (b < C8)  { src = s7; dst = d7; n = 128;     lb = b - C7; }
    else if (b < C9)  { src = s8; dst = d8; n = 49152;   lb = b - C8; }
    else              { src = s9; dst = d9; n = 128;     lb = b - C9; }
    int i = lb * 256 + threadIdx.x;
    if (i < n) {
        if (flags[0]) dst[i] = f2bf(((const float*)src)[i]);
        else          dst[i] = ((const bf16*)src)[i];
    }
}

#define B_E 4688
__global__ void k_cvt_ints(const int* __restrict__ flags, const int* __restrict__ e,
                           const int* __restrict__ cc, int* __restrict__ ec,
                           int* __restrict__ ccc) {
    int i64 = flags[1];
    int b = blockIdx.x;
    if (b < B_E) {
        int i = b * 256 + threadIdx.x;
        if (i < 2 * N_EDGES) ec[i] = i64 ? e[2 * i] : e[i];
    } else {
        int i = (b - B_E) * 256 + threadIdx.x;
        if (i < N_NODES) ccc[i] = i64 ? cc[2 * i] : cc[i];
    }
}

// ====== composed-weight prep: Wc[wcol][0:384] bf16, bc[wcol] fp32 ======
// kk<128:   Wc = Wu_x + Wm_x @ Wu_a     (upd's x path absorbs message MLP's x path)
// 128..255: Wc = Wm_m @ Wu_a            (message's mean-neighbor path)
// 256..383: Wc = Wu_p                   (pool path)
// bc = bu + bm @ Wu_a
__global__ void k_prep2(const bf16* __restrict__ Wm, const bf16* __restrict__ Wu,
                        const bf16* __restrict__ bm, const bf16* __restrict__ bu,
                        bf16* __restrict__ Wc, float* __restrict__ bc) {
    int b = blockIdx.x;
    if (b < 192) {
        int i = b * 256 + threadIdx.x;  // < 49152
        int w = i / 384, kk = i - w * 384;
        float acc = 0.f;
        if (kk < 128) {
            acc = bf2f(Wu[kk * 128 + w]);
            for (int j = 0; j < 128; j++)
                acc += bf2f(Wm[kk * 128 + j]) * bf2f(Wu[(128 + j) * 128 + w]);
        } else if (kk < 256) {
            int kp = kk - 128;
            for (int j = 0; j < 128; j++)
                acc += bf2f(Wm[(128 + kp) * 128 + j]) * bf2f(Wu[(128 + j) * 128 + w]);
        } else {
            acc = bf2f(Wu[kk * 128 + w]);
        }
        Wc[w * 384 + kk] = f2bf(acc);
    } else {
        int w = threadIdx.x;
        if (w < 128) {
            float acc = bf2f(bu[w]);
            for (int j = 0; j < 128; j++)
                acc += bf2f(bm[j]) * bf2f(Wu[(128 + j) * 128 + w]);
            bc[w] = acc;
        }
    }
}

// ================= encoder =================
__global__ void k_encoder(const bf16* __restrict__ cf, const bf16* __restrict__ slf,
                          const bf16* __restrict__ z, const bf16* __restrict__ W,
                          const bf16* __restrict__ b, float* __restrict__ x,
                          bf16* __restrict__ xb) {
    __shared__ float in[2][48];
    int half = threadIdx.x >> 7, t = threadIdx.x & 127;
    int node = blockIdx.x * 2 + half;
    if (t < 48) {
        float v;
        if (t < 15) v = bf2f(cf[node * 15 + t]);
        else if (t == 15) v = bf2f(slf[node]);
        else v = bf2f(z[node * 32 + (t - 16)]);
        in[half][t] = v;
    }
    __syncthreads();
    float acc = bf2f(b[t]);
#pragma unroll 8
    for (int k = 0; k < 48; k++) acc += in[half][k] * bf2f(W[k * 128 + t]);
    size_t idx = (size_t)node * HD + t;
    x[idx] = acc;
    xb[idx] = f2bf(acc);
}

// ================= CSR build =================
__global__ void k_count_edges(const int* __restrict__ e, int* __restrict__ deg) {
    int i = blockIdx.x * 256 + threadIdx.x;
    if (i < N_EDGES) atomicAdd(&deg[e[N_EDGES + i]], 1);
}
__global__ void k_count_nodes(const int* __restrict__ cc, int* __restrict__ ccount) {
    int i = blockIdx.x * 256 + threadIdx.x;
    if (i < N_NODES) atomicAdd(&ccount[cc[i]], 1);
}

__global__ void k_scan_a(const int* __restrict__ deg, int* __restrict__ rowptr,
                         int* __restrict__ bsum) {
    __shared__ int sd[1024];
    int t = threadIdx.x;
    int i = blockIdx.x * 1024 + t;
    int v = (i < N_NODES) ? deg[i] : 0;
    sd[t] = v;
    __syncthreads();
#pragma unroll
    for (int off = 1; off < 1024; off <<= 1) {
        int u = (t >= off) ? sd[t - off] : 0;
        __syncthreads();
        sd[t] += u;
        __syncthreads();
    }
    if (i < N_NODES) rowptr[i] = sd[t] - v;
    if (t == 1023) bsum[blockIdx.x] = sd[t];
}
__global__ void k_scan_b(const int* __restrict__ bsum, int* __restrict__ boff,
                         int* __restrict__ rowptr) {
    __shared__ int sd[128];
    int t = threadIdx.x;
    int v = (t < SCAN_B) ? bsum[t] : 0;
    sd[t] = v;
    __syncthreads();
#pragma unroll
    for (int off = 1; off < 128; off <<= 1) {
        int u = (t >= off) ? sd[t - off] : 0;
        __syncthreads();
        sd[t] += u;
        __syncthreads();
    }
    if (t < SCAN_B) boff[t] = sd[t] - v;
    if (t == 0) rowptr[N_NODES] = N_EDGES;
}
__global__ void k_scan_c(int* __restrict__ rowptr, int* __restrict__ cursor,
                         const int* __restrict__ boff) {
    int i = blockIdx.x * 1024 + threadIdx.x;
    if (i < N_NODES) {
        int r = rowptr[i] + boff[blockIdx.x];
        rowptr[i] = r;
        cursor[i] = r;
    }
}

__global__ void k_scan_clusters(const int* __restrict__ ccount, int* __restrict__ coff,
                                int* __restrict__ ccur) {
    __shared__ int sd[512];
    int t = threadIdx.x;
    sd[t] = (t < NBC) ? ccount[t] : 0;
    __syncthreads();
    for (int off = 1; off < 512; off <<= 1) {
        int v = (t >= off) ? sd[t - off] : 0;
        __syncthreads();
        sd[t] += v;
        __syncthreads();
    }
    if (t < NBC) {
        int ex = (t == 0) ? 0 : sd[t - 1];
        coff[t] = ex;
        ccur[t] = ex;
        if (t == NBC - 1) coff[NBC] = sd[t];
    }
}

__global__ void k_fill_edges(const int* __restrict__ e, int* __restrict__ cursor,
                             int* __restrict__ colx) {
    int i = blockIdx.x * 256 + threadIdx.x;
    if (i < N_EDGES) {
        int d = e[N_EDGES + i];
        int p = atomicAdd(&cursor[d], 1);
        colx[p] = e[i];
    }
}
__global__ void k_fill_nodes(const int* __restrict__ cc, int* __restrict__ ccur,
                             int* __restrict__ cnodes) {
    int i = blockIdx.x * 256 + threadIdx.x;
    if (i < N_NODES) {
        int p = atomicAdd(&ccur[cc[i]], 1);
        cnodes[p] = i;
    }
}

// deg==0 node list (exceptions to the linear folding)
__global__ void k_list0(const int* __restrict__ deg, int* __restrict__ n0list,
                        int* __restrict__ n0cnt) {
    int i = blockIdx.x * 256 + threadIdx.x;
    if (i < N_NODES && deg[i] == 0) {
        int p = atomicAdd(n0cnt, 1);
        if (p < MAXFIX) n0list[p] = i;
    }
}

// ================= per-layer: mean of x[src] over incoming edges =================
__global__ void k_aggregate(const bf16* __restrict__ xb, const int* __restrict__ rowptr,
                            const int* __restrict__ colx, bf16* __restrict__ mb) {
    int wave = threadIdx.x >> 6, lane = threadIdx.x & 63;
    int node = blockIdx.x * 4 + wave;
    if (node >= N_NODES) return;
    int lo = rowptr[node], hi = rowptr[node + 1];
    float a0 = 0.f, a1 = 0.f;
    int j = lo;
    while (j + 2 <= hi) {
        int s0 = colx[j], s1 = colx[j + 1];
        __hip_bfloat162 v0 = *((const __hip_bfloat162*)(xb + (size_t)s0 * HD) + lane);
        __hip_bfloat162 v1 = *((const __hip_bfloat162*)(xb + (size_t)s1 * HD) + lane);
        a0 += bf2f(v0.x) + bf2f(v1.x);
        a1 += bf2f(v0.y) + bf2f(v1.y);
        j += 2;
    }
    if (j < hi) {
        int s0 = colx[j];
        __hip_bfloat162 v0 = *((const __hip_bfloat162*)(xb + (size_t)s0 * HD) + lane);
        a0 += bf2f(v0.x);
        a1 += bf2f(v0.y);
    }
    int d = hi - lo;
    float inv = 1.0f / (float)(d > 1 ? d : 1);
    __hip_bfloat162 o;
    o.x = f2bf(a0 * inv);
    o.y = f2bf(a1 * inv);
    *((__hip_bfloat162*)(mb + (size_t)node * HD) + lane) = o;
}

// ================= per-layer: cluster pooling =================
__global__ void k_pool_partial(const float* __restrict__ x, const int* __restrict__ coff,
                               const int* __restrict__ cnodes, float* __restrict__ pf) {
    int cl = blockIdx.x >> 2, seg = blockIdx.x & 3;
    int lo = coff[cl], hi = coff[cl + 1];
    int cnt = hi - lo;
    int per = (cnt + 3) >> 2;
    int s0 = lo + seg * per;
    int s1 = min(s0 + per, hi);
    int col = threadIdx.x & 127, half = threadIdx.x >> 7;
    float a = 0.f;
    for (int i = s0 + half; i < s1; i += 2) a += x[(size_t)cnodes[i] * HD + col];
    __shared__ float red[256];
    red[threadIdx.x] = a;
    __syncthreads();
    if (half == 0) {
        float s = red[col] + red[col + 128];
        atomicAdd(&pf[cl * HD + col], s);
    }
}
__global__ void k_pool_final(const float* __restrict__ pf, const int* __restrict__ ccount,
                             const bf16* __restrict__ tr, bf16* __restrict__ pooled) {
    int i = blockIdx.x * 256 + threadIdx.x;
    int cl = i >> 7;
    int c = ccount[cl];
    float v = pf[i] / (float)(c > 1 ? c : 1) * bf2f(tr[cl]);
    pooled[i] = f2bf(v);
}

// ===== deg-0 fixup: exact upd for nodes where the linear folding is wrong =====
// runs BEFORE k_fused (reads old x), stashes corrected new-x rows.
__global__ void k_fix_pre(const bf16* __restrict__ xb, const bf16* __restrict__ pooled,
                          const bf16* __restrict__ Wu, const bf16* __restrict__ bu,
                          const int* __restrict__ cc, const float* __restrict__ x,
                          const int* __restrict__ n0list, const int* __restrict__ n0cnt,
                          float* __restrict__ stash) {
    __shared__ float xv[128], pv[128];
    int cnt = min(*n0cnt, MAXFIX);
    int col = threadIdx.x;
    for (int j = blockIdx.x; j < cnt; j += 256) {
        int v = n0list[j];
        xv[col] = bf2f(xb[(size_t)v * HD + col]);
        pv[col] = bf2f(pooled[cc[v] * HD + col]);
        __syncthreads();
        float acc = bf2f(bu[col]);
        for (int k = 0; k < 128; k++)
            acc += xv[k] * bf2f(Wu[k * 128 + col]) + pv[k] * bf2f(Wu[(256 + k) * 128 + col]);
        float u = acc > 0.f ? acc : 0.01f * acc;
        stash[j * 128 + col] = x[(size_t)v * HD + col] + u;
        __syncthreads();
    }
}
__global__ void k_fix_post(const int* __restrict__ n0list, const int* __restrict__ n0cnt,
                           const float* __restrict__ stash, float* __restrict__ x,
                           bf16* __restrict__ xbo, const int* __restrict__ flags,
                           void* __restrict__ out, int last) {
    int cnt = min(*n0cnt, MAXFIX);
    int col = threadIdx.x;
    int fp32out = flags[0];
    for (int j = blockIdx.x; j < cnt; j += 256) {
        int v = n0list[j];
        float nv = stash[j * 128 + col];
        size_t idx = (size_t)v * HD + col;
        if (last) {
            if (fp32out) ((float*)out)[idx] = nv;
            else ((bf16*)out)[idx] = f2bf(nv);
        } else {
            x[idx] = nv;
            xbo[idx] = f2bf(nv);
        }
    }
}

// ================= per-layer fused update: ONE K=384 GEMM, no LDS, no barriers ====
// upd = leaky( x@W1 + m@W2 + pooled[cc]@W3 + b' );  x += upd  (wrong only for deg-0
// rows, fixed by k_fix_pre/post). MFMA operands SWAPPED (weights as A) so D is
// transposed: each lane holds 4 consecutive cols of one row -> float4 epilogue.
__global__ __launch_bounds__(256) void k_fused(
    const bf16* __restrict__ xb, const bf16* __restrict__ mb, const bf16* __restrict__ pooled,
    const bf16* __restrict__ Wc, const float* __restrict__ bc,
    const int* __restrict__ cc, float* __restrict__ x, bf16* __restrict__ xbo,
    const int* __restrict__ flags, void* __restrict__ out, int last) {
    int tid = threadIdx.x;
    int r0 = blockIdx.x * 64;
    int wave = tid >> 6, lane = tid & 63, quad = lane >> 4, nidx = lane & 15;
    int colbase = wave * 32;

    int arow[4];
#pragma unroll
    for (int rt = 0; rt < 4; rt++) {
        int gr = r0 + rt * 16 + nidx;
        arow[rt] = (gr < N_NODES) ? gr : (N_NODES - 1);
    }
    int cci[4];
#pragma unroll
    for (int rt = 0; rt < 4; rt++) cci[rt] = cc[arow[rt]];

    f4v acc[4][2];
#pragma unroll
    for (int rt = 0; rt < 4; rt++)
#pragma unroll
        for (int ct = 0; ct < 2; ct++) acc[rt][ct] = (f4v){0.f, 0.f, 0.f, 0.f};

#pragma unroll
    for (int s = 0; s < 12; s++) {
        int k0 = s * 32;
        s8v bfrag[4];
        if (s < 4) {
#pragma unroll
            for (int rt = 0; rt < 4; rt++)
                bfrag[rt] = *(const s8v*)((const short*)xb + (size_t)arow[rt] * HD + k0 + quad * 8);
        } else if (s < 8) {
            int kk = k0 - 128;
#pragma unroll
            for (int rt = 0; rt < 4; rt++)
                bfrag[rt] = *(const s8v*)((const short*)mb + (size_t)arow[rt] * HD + kk + quad * 8);
        } else {
            int kk = k0 - 256;
#pragma unroll
            for (int rt = 0; rt < 4; rt++)
                bfrag[rt] = *(const s8v*)((const short*)pooled + (size_t)cci[rt] * HD + kk + quad * 8);
        }
#pragma unroll
        for (int ct = 0; ct < 2; ct++) {
            s8v wfr = *(const s8v*)((const short*)Wc + (colbase + ct * 16 + nidx) * 384 + k0 + quad * 8);
#pragma unroll
            for (int rt = 0; rt < 4; rt++)
                acc[rt][ct] = __builtin_amdgcn_mfma_f32_16x16x32_bf16(wfr, bfrag[rt], acc[rt][ct], 0, 0, 0);
        }
    }

    // epilogue: D[m=wcol=quad*4+r (per ct)][n=xrow=nidx (per rt)] -> float4 RMW
    int fp32out = flags[0];
#pragma unroll
    for (int rt = 0; rt < 4; rt++) {
        int gr = r0 + rt * 16 + nidx;
        if (gr < N_NODES) {
#pragma unroll
            for (int ct = 0; ct < 2; ct++) {
                int wc0 = colbase + ct * 16 + quad * 4;
                f4v bv = *(const f4v*)(bc + wc0);
                size_t idx = (size_t)gr * HD + wc0;
                f4v xo = *(const f4v*)(x + idx);
                f4v nv;
#pragma unroll
                for (int r = 0; r < 4; r++) {
                    float v = acc[rt][ct][r] + bv[r];
                    v = (v > 0.f) ? v : 0.01f * v;
                    nv[r] = xo[r] + v;
                }
                if (last) {
                    if (fp32out) {
                        *(f4v*)((float*)out + idx) = nv;
                    } else {
                        s4v ob;
#pragma unroll
                        for (int r = 0; r < 4; r++) { bf16 h = f2bf(nv[r]); ob[r] = *(short*)&h; }
                        *(s4v*)((short*)out + idx) = ob;
                    }
                } else {
                    *(f4v*)(x + idx) = nv;
                    s4v ob;
#pragma unroll
                    for (int r = 0; r < 4; r++) { bf16 h = f2bf(nv[r]); ob[r] = *(short*)&h; }
                    *(s4v*)((short*)xbo + idx) = ob;
                }
            }
        }
    }
}

extern "C" void kernel_launch(void* const* d_in, const int* in_sizes, int n_in,
                              void* d_out, int out_size, void* d_ws, size_t ws_size,
                              hipStream_t stream) {
    const void* cf_r = d_in[0];
    const void* slf_r = d_in[1];
    const void* z_r = d_in[2];
    const void* tr_r = d_in[3];
    const void* Wenc_r = d_in[4];
    const void* benc_r = d_in[5];
    const void* Wm_r = d_in[6];
    const void* bm_r = d_in[7];
    const void* Wu_r = d_in[8];
    const void* bu_r = d_in[9];
    const int* e_r = (const int*)d_in[10];
    const int* cc_r = (const int*)d_in[11];

    char* w = (char*)d_ws;
    auto alloc = [&](size_t bytes) -> char* {
        char* p = w;
        w += (bytes + 63) & ~(size_t)63;
        return p;
    };
    float* x = (float*)alloc((size_t)N_NODES * HD * 4);
    bf16* xb0 = (bf16*)alloc((size_t)N_NODES * HD * 2);
    bf16* xb1 = (bf16*)alloc((size_t)N_NODES * HD * 2);
    bf16* mb = (bf16*)alloc((size_t)N_NODES * HD * 2);
    bf16* Wc = (bf16*)alloc(128 * 384 * 2);
    float* bc = (float*)alloc(128 * 4);
    float* pooledf = (float*)alloc(NBC * HD * 4);
    bf16* pooled = (bf16*)alloc(NBC * HD * 2);
    int* deg = (int*)alloc(N_NODES * 4);
    int* rowptr = (int*)alloc((N_NODES + 1) * 4);
    int* cursor = (int*)alloc(N_NODES * 4);
    int* colx = (int*)alloc(N_EDGES * 4);
    int* ccount = (int*)alloc(NBC * 4);
    int* coff = (int*)alloc((NBC + 1) * 4);
    int* ccur = (int*)alloc(NBC * 4);
    int* cnodes = (int*)alloc(N_NODES * 4);
    int* flags = (int*)alloc(64);
    int* bsum = (int*)alloc(SCAN_B * 4);
    int* boff = (int*)alloc(SCAN_B * 4);
    int* n0list = (int*)alloc(MAXFIX * 4);
    int* n0cnt = (int*)alloc(64);
    float* stash = (float*)alloc((size_t)MAXFIX * HD * 4);
    bf16* cfc = (bf16*)alloc(1500000 * 2);
    bf16* slfc = (bf16*)alloc(100000 * 2);
    bf16* zc = (bf16*)alloc(3200000 * 2);
    bf16* trc = (bf16*)alloc(384 * 2);
    bf16* Wencc = (bf16*)alloc(6144 * 2);
    bf16* bencc = (bf16*)alloc(128 * 2);
    bf16* Wmc = (bf16*)alloc(32768 * 2);
    bf16* bmc = (bf16*)alloc(128 * 2);
    bf16* Wuc = (bf16*)alloc(49152 * 2);
    bf16* buc = (bf16*)alloc(128 * 2);
    int* ec = (int*)alloc(2 * N_EDGES * 4);
    int* ccc = (int*)alloc(N_NODES * 4);

    // dtype detection + canonical conversion
    k_detect<<<1, 64, 0, stream>>>((const unsigned short*)Wenc_r, e_r, flags);
    k_cvt_all<<<C10, 256, 0, stream>>>(flags, cf_r, slf_r, z_r, tr_r, Wenc_r, benc_r,
                                       Wm_r, bm_r, Wu_r, bu_r,
                                       cfc, slfc, zc, trc, Wencc, bencc, Wmc, bmc, Wuc, buc);
    k_cvt_ints<<<B_E + 391, 256, 0, stream>>>(flags, e_r, cc_r, ec, ccc);

    // composed weights + encoder
    k_prep2<<<193, 256, 0, stream>>>(Wmc, Wuc, bmc, buc, Wc, bc);
    k_encoder<<<N_NODES / 2, 256, 0, stream>>>(cfc, slfc, zc, Wencc, bencc, x, xb0);

    // CSR build
    hipMemsetAsync(deg, 0, (size_t)N_NODES * 4, stream);
    hipMemsetAsync(ccount, 0, (size_t)NBC * 4, stream);
    hipMemsetAsync(n0cnt, 0, 64, stream);
    k_count_edges<<<(N_EDGES + 255) / 256, 256, 0, stream>>>(ec, deg);
    k_count_nodes<<<(N_NODES + 255) / 256, 256, 0, stream>>>(ccc, ccount);
    k_scan_a<<<SCAN_B, 1024, 0, stream>>>(deg, rowptr, bsum);
    k_scan_b<<<1, 128, 0, stream>>>(bsum, boff, rowptr);
    k_scan_c<<<SCAN_B, 1024, 0, stream>>>(rowptr, cursor, boff);
    k_scan_clusters<<<1, 512, 0, stream>>>(ccount, coff, ccur);
    k_fill_edges<<<(N_EDGES + 255) / 256, 256, 0, stream>>>(ec, cursor, colx);
    k_fill_nodes<<<(N_NODES + 255) / 256, 256, 0, stream>>>(ccc, ccur, cnodes);
    k_list0<<<(N_NODES + 255) / 256, 256, 0, stream>>>(deg, n0list, n0cnt);

    bf16* xbufs[2] = {xb0, xb1};
    for (int layer = 0; layer < 3; layer++) {
        bf16* xbi = xbufs[layer & 1];
        bf16* xbo = xbufs[(layer + 1) & 1];
        int last = (layer == 2);
        hipMemsetAsync(pooledf, 0, (size_t)NBC * HD * 4, stream);
        k_aggregate<<<N_NODES / 4, 256, 0, stream>>>(xbi, rowptr, colx, mb);
        k_pool_partial<<<NBC * 4, 256, 0, stream>>>(x, coff, cnodes, pooledf);
        k_pool_final<<<NBC * HD / 256, 256, 0, stream>>>(pooledf, ccount, trc, pooled);
        k_fix_pre<<<256, 128, 0, stream>>>(xbi, pooled, Wuc, buc, ccc, x,
                                           n0list, n0cnt, stash);
        k_fused<<<(N_NODES + 63) / 64, 256, 0, stream>>>(xbi, mb, pooled, Wc, bc,
                                                         ccc, x, xbo, flags, d_out, last);
        k_fix_post<<<256, 128, 0, stream>>>(n0list, n0cnt, stash, x, xbo,
                                            flags, d_out, last);
    }
}

// Round 6
// 783.833 us; speedup vs baseline: 1.1654x; 1.0706x over previous
//
#include <hip/hip_runtime.h>
#include <hip/hip_bf16.h>

#define N_NODES 100000
#define N_EDGES 600000
#define HD 128
#define NBC 384
#define SCAN_B 98   // ceil(N_NODES/1024)
#define MAXFIX 4096 // cap on deg-0 fixup list (E[count]~250 for Poisson(6))

typedef __attribute__((ext_vector_type(8))) short s8v;
typedef __attribute__((ext_vector_type(4))) short s4v;
typedef __attribute__((ext_vector_type(4))) float f4v;
typedef __hip_bfloat16 bf16;

static __device__ __forceinline__ float bf2f(bf16 v) { return __bfloat162float(v); }
static __device__ __forceinline__ bf16 f2bf(float v) { return __float2bfloat16(v); }

// ================= dtype detection =================
__global__ void k_detect(const unsigned short* __restrict__ wraw,
                         const int* __restrict__ eraw, int* __restrict__ flags) {
    if (threadIdx.x == 0 && blockIdx.x == 0) {
        int fp32 = 0;
        for (int i = 0; i < 1024; i++) {
            unsigned int u = ((unsigned int)wraw[i]) << 16;
            float f = fabsf(__uint_as_float(u));
            if (!(f <= 1e4f)) fp32 = 1;  // catches huge AND NaN
        }
        int i64 = (eraw[1] == 0 && eraw[3] == 0 && eraw[5] == 0 && eraw[7] == 0) ? 1 : 0;
        flags[0] = fp32;
        flags[1] = i64;
    }
}

// ========== canonical conversion; cf/slf/z packed into xin[N][64] (bf16) ==========
// xin cols: 0-14 cf, 15 slf, 16-47 z, 48-63 zero (memset'd before this kernel)
#define B_CF 5860
#define C1 (B_CF)
#define C2 (C1 + 391)
#define C3 (C2 + 12500)
#define C4 (C3 + 2)
#define C5 (C4 + 24)
#define C6 (C5 + 1)
#define C7 (C6 + 128)
#define C8 (C7 + 1)
#define C9 (C8 + 192)
#define C10 (C9 + 1)
__global__ void k_cvt_all(const int* __restrict__ flags,
                          const void* s0, const void* s1, const void* s2, const void* s3,
                          const void* s4, const void* s5, const void* s6, const void* s7,
                          const void* s8, const void* s9,
                          bf16* __restrict__ xin,
                          bf16* d3, bf16* d4, bf16* d5, bf16* d6, bf16* d7,
                          bf16* d8, bf16* d9) {
    int b = blockIdx.x;
    int fp32 = flags[0];
    if (b < C3) {
        // packed input ranges
        const void* src; int n, lb, range;
        if (b < C1)      { src = s0; n = 1500000; lb = b;      range = 0; }
        else if (b < C2) { src = s1; n = 100000;  lb = b - C1; range = 1; }
        else             { src = s2; n = 3200000; lb = b - C2; range = 2; }
        int i = lb * 256 + threadIdx.x;
        if (i < n) {
            float v = fp32 ? ((const float*)src)[i] : bf2f(((const bf16*)src)[i]);
            size_t di;
            if (range == 0)      { int node = i / 15; di = (size_t)node * 64 + (i - node * 15); }
            else if (range == 1) { di = (size_t)i * 64 + 15; }
            else                 { di = (size_t)(i >> 5) * 64 + 16 + (i & 31); }
            xin[di] = f2bf(v);
        }
        return;
    }
    const void* src; bf16* dst; int n, lb;
    if (b < C4)       { src = s3; dst = d3; n = 384;   lb = b - C3; }
    else if (b < C5)  { src = s4; dst = d4; n = 6144;  lb = b - C4; }
    else if (b < C6)  { src = s5; dst = d5; n = 128;   lb = b - C5; }
    else if (b < C7)  { src = s6; dst = d6; n = 32768; lb = b - C6; }
    else if (b < C8)  { src = s7; dst = d7; n = 128;   lb = b - C7; }
    else if (b < C9)  { src = s8; dst = d8; n = 49152; lb = b - C8; }
    else              { src = s9; dst = d9; n = 128;   lb = b - C9; }
    int i = lb * 256 + threadIdx.x;
    if (i < n) {
        if (fp32) dst[i] = f2bf(((const float*)src)[i]);
        else      dst[i] = ((const bf16*)src)[i];
    }
}

#define B_E 4688
__global__ void k_cvt_ints(const int* __restrict__ flags, const int* __restrict__ e,
                           const int* __restrict__ cc, int* __restrict__ ec,
                           int* __restrict__ ccc) {
    int i64 = flags[1];
    int b = blockIdx.x;
    if (b < B_E) {
        int i = b * 256 + threadIdx.x;
        if (i < 2 * N_EDGES) ec[i] = i64 ? e[2 * i] : e[i];
    } else {
        int i = (b - B_E) * 256 + threadIdx.x;
        if (i < N_NODES) ccc[i] = i64 ? cc[2 * i] : cc[i];
    }
}

// ====== composed-weight prep ======
// b<192:  Wc[w][kk] (K=384 fused update weights, transposed, composed)
// b in [192,224): Wet[w][kk] = Wenc[kk][w] zero-padded to K=64
// b==224: bc (fused bias, fp32) + bcenc (encoder bias, fp32)
__global__ void k_prep2(const bf16* __restrict__ Wm, const bf16* __restrict__ Wu,
                        const bf16* __restrict__ bm, const bf16* __restrict__ bu,
                        const bf16* __restrict__ Wenc, const bf16* __restrict__ benc,
                        bf16* __restrict__ Wc, float* __restrict__ bc,
                        bf16* __restrict__ Wet, float* __restrict__ bcenc) {
    int b = blockIdx.x;
    if (b < 192) {
        int i = b * 256 + threadIdx.x;  // < 49152
        int w = i / 384, kk = i - w * 384;
        float acc = 0.f;
        if (kk < 128) {
            acc = bf2f(Wu[kk * 128 + w]);
            for (int j = 0; j < 128; j++)
                acc += bf2f(Wm[kk * 128 + j]) * bf2f(Wu[(128 + j) * 128 + w]);
        } else if (kk < 256) {
            int kp = kk - 128;
            for (int j = 0; j < 128; j++)
                acc += bf2f(Wm[(128 + kp) * 128 + j]) * bf2f(Wu[(128 + j) * 128 + w]);
        } else {
            acc = bf2f(Wu[kk * 128 + w]);
        }
        Wc[w * 384 + kk] = f2bf(acc);
    } else if (b < 224) {
        int i = (b - 192) * 256 + threadIdx.x;  // < 8192
        int w = i >> 6, kk = i & 63;
        bf16 zero; { float zf = 0.f; zero = f2bf(zf); }
        Wet[i] = (kk < 48) ? Wenc[kk * 128 + w] : zero;
    } else {
        int t = threadIdx.x;
        if (t < 128) {
            float acc = bf2f(bu[t]);
            for (int j = 0; j < 128; j++)
                acc += bf2f(bm[j]) * bf2f(Wu[(128 + j) * 128 + t]);
            bc[t] = acc;
        } else {
            bcenc[t - 128] = bf2f(benc[t - 128]);
        }
    }
}

// ================= MFMA encoder: x = xin[N,64] @ Wet^T + benc =================
// same swapped-operand pattern as k_fused: A=weights, B=x-rows -> transposed D,
// float4 epilogue (lane holds 4 consecutive cols of one row).
__global__ __launch_bounds__(256) void k_encoder_mfma(
    const bf16* __restrict__ xin, const bf16* __restrict__ Wet,
    const float* __restrict__ bcenc, float* __restrict__ x, bf16* __restrict__ xb) {
    int tid = threadIdx.x;
    int r0 = blockIdx.x * 64;
    int wave = tid >> 6, lane = tid & 63, quad = lane >> 4, nidx = lane & 15;
    int colbase = wave * 32;

    int arow[4];
#pragma unroll
    for (int rt = 0; rt < 4; rt++) {
        int gr = r0 + rt * 16 + nidx;
        arow[rt] = (gr < N_NODES) ? gr : (N_NODES - 1);
    }
    f4v acc[4][2];
#pragma unroll
    for (int rt = 0; rt < 4; rt++)
#pragma unroll
        for (int ct = 0; ct < 2; ct++) acc[rt][ct] = (f4v){0.f, 0.f, 0.f, 0.f};

#pragma unroll
    for (int s = 0; s < 2; s++) {
        int k0 = s * 32;
        s8v bfrag[4];
#pragma unroll
        for (int rt = 0; rt < 4; rt++)
            bfrag[rt] = *(const s8v*)((const short*)xin + (size_t)arow[rt] * 64 + k0 + quad * 8);
#pragma unroll
        for (int ct = 0; ct < 2; ct++) {
            s8v wfr = *(const s8v*)((const short*)Wet + (colbase + ct * 16 + nidx) * 64 + k0 + quad * 8);
#pragma unroll
            for (int rt = 0; rt < 4; rt++)
                acc[rt][ct] = __builtin_amdgcn_mfma_f32_16x16x32_bf16(wfr, bfrag[rt], acc[rt][ct], 0, 0, 0);
        }
    }
#pragma unroll
    for (int rt = 0; rt < 4; rt++) {
        int gr = r0 + rt * 16 + nidx;
        if (gr < N_NODES) {
#pragma unroll
            for (int ct = 0; ct < 2; ct++) {
                int wc0 = colbase + ct * 16 + quad * 4;
                f4v bv = *(const f4v*)(bcenc + wc0);
                size_t idx = (size_t)gr * HD + wc0;
                f4v nv;
                s4v ob;
#pragma unroll
                for (int r = 0; r < 4; r++) {
                    nv[r] = acc[rt][ct][r] + bv[r];
                    bf16 h = f2bf(nv[r]);
                    ob[r] = *(short*)&h;
                }
                *(f4v*)(x + idx) = nv;
                *(s4v*)((short*)xb + idx) = ob;
            }
        }
    }
}

// ================= CSR build =================
__global__ void k_count_edges(const int* __restrict__ e, int* __restrict__ deg) {
    int i = blockIdx.x * 256 + threadIdx.x;
    if (i < N_EDGES) atomicAdd(&deg[e[N_EDGES + i]], 1);
}
__global__ void k_count_nodes(const int* __restrict__ cc, int* __restrict__ ccount) {
    int i = blockIdx.x * 256 + threadIdx.x;
    if (i < N_NODES) atomicAdd(&ccount[cc[i]], 1);
}

__global__ void k_scan_a(const int* __restrict__ deg, int* __restrict__ rowptr,
                         int* __restrict__ bsum) {
    __shared__ int sd[1024];
    int t = threadIdx.x;
    int i = blockIdx.x * 1024 + t;
    int v = (i < N_NODES) ? deg[i] : 0;
    sd[t] = v;
    __syncthreads();
#pragma unroll
    for (int off = 1; off < 1024; off <<= 1) {
        int u = (t >= off) ? sd[t - off] : 0;
        __syncthreads();
        sd[t] += u;
        __syncthreads();
    }
    if (i < N_NODES) rowptr[i] = sd[t] - v;
    if (t == 1023) bsum[blockIdx.x] = sd[t];
}
__global__ void k_scan_b(const int* __restrict__ bsum, int* __restrict__ boff,
                         int* __restrict__ rowptr) {
    __shared__ int sd[128];
    int t = threadIdx.x;
    int v = (t < SCAN_B) ? bsum[t] : 0;
    sd[t] = v;
    __syncthreads();
#pragma unroll
    for (int off = 1; off < 128; off <<= 1) {
        int u = (t >= off) ? sd[t - off] : 0;
        __syncthreads();
        sd[t] += u;
        __syncthreads();
    }
    if (t < SCAN_B) boff[t] = sd[t] - v;
    if (t == 0) rowptr[N_NODES] = N_EDGES;
}
__global__ void k_scan_c(int* __restrict__ rowptr, int* __restrict__ cursor,
                         const int* __restrict__ boff) {
    int i = blockIdx.x * 1024 + threadIdx.x;
    if (i < N_NODES) {
        int r = rowptr[i] + boff[blockIdx.x];
        rowptr[i] = r;
        cursor[i] = r;
    }
}

__global__ void k_scan_clusters(const int* __restrict__ ccount, int* __restrict__ coff,
                                int* __restrict__ ccur) {
    __shared__ int sd[512];
    int t = threadIdx.x;
    sd[t] = (t < NBC) ? ccount[t] : 0;
    __syncthreads();
    for (int off = 1; off < 512; off <<= 1) {
        int v = (t >= off) ? sd[t - off] : 0;
        __syncthreads();
        sd[t] += v;
        __syncthreads();
    }
    if (t < NBC) {
        int ex = (t == 0) ? 0 : sd[t - 1];
        coff[t] = ex;
        ccur[t] = ex;
        if (t == NBC - 1) coff[NBC] = sd[t];
    }
}

__global__ void k_fill_edges(const int* __restrict__ e, int* __restrict__ cursor,
                             int* __restrict__ colx) {
    int i = blockIdx.x * 256 + threadIdx.x;
    if (i < N_EDGES) {
        int d = e[N_EDGES + i];
        int p = atomicAdd(&cursor[d], 1);
        colx[p] = e[i];
    }
}
__global__ void k_fill_nodes(const int* __restrict__ cc, int* __restrict__ ccur,
                             int* __restrict__ cnodes) {
    int i = blockIdx.x * 256 + threadIdx.x;
    if (i < N_NODES) {
        int p = atomicAdd(&ccur[cc[i]], 1);
        cnodes[p] = i;
    }
}

__global__ void k_list0(const int* __restrict__ deg, int* __restrict__ n0list,
                        int* __restrict__ n0cnt) {
    int i = blockIdx.x * 256 + threadIdx.x;
    if (i < N_NODES && deg[i] == 0) {
        int p = atomicAdd(n0cnt, 1);
        if (p < MAXFIX) n0list[p] = i;
    }
}

// ================= per-layer: mean of x[src] over incoming edges =================
__global__ void k_aggregate(const bf16* __restrict__ xb, const int* __restrict__ rowptr,
                            const int* __restrict__ colx, bf16* __restrict__ mb) {
    int wave = threadIdx.x >> 6, lane = threadIdx.x & 63;
    int node = blockIdx.x * 4 + wave;
    if (node >= N_NODES) return;
    int lo = rowptr[node], hi = rowptr[node + 1];
    float a0 = 0.f, a1 = 0.f;
    int j = lo;
    while (j + 2 <= hi) {
        int s0 = colx[j], s1 = colx[j + 1];
        __hip_bfloat162 v0 = *((const __hip_bfloat162*)(xb + (size_t)s0 * HD) + lane);
        __hip_bfloat162 v1 = *((const __hip_bfloat162*)(xb + (size_t)s1 * HD) + lane);
        a0 += bf2f(v0.x) + bf2f(v1.x);
        a1 += bf2f(v0.y) + bf2f(v1.y);
        j += 2;
    }
    if (j < hi) {
        int s0 = colx[j];
        __hip_bfloat162 v0 = *((const __hip_bfloat162*)(xb + (size_t)s0 * HD) + lane);
        a0 += bf2f(v0.x);
        a1 += bf2f(v0.y);
    }
    int d = hi - lo;
    float inv = 1.0f / (float)(d > 1 ? d : 1);
    __hip_bfloat162 o;
    o.x = f2bf(a0 * inv);
    o.y = f2bf(a1 * inv);
    *((__hip_bfloat162*)(mb + (size_t)node * HD) + lane) = o;
}

// ================= per-layer: cluster pooling =================
__global__ void k_pool_partial(const float* __restrict__ x, const int* __restrict__ coff,
                               const int* __restrict__ cnodes, float* __restrict__ pf) {
    int cl = blockIdx.x >> 2, seg = blockIdx.x & 3;
    int lo = coff[cl], hi = coff[cl + 1];
    int cnt = hi - lo;
    int per = (cnt + 3) >> 2;
    int s0 = lo + seg * per;
    int s1 = min(s0 + per, hi);
    int col = threadIdx.x & 127, half = threadIdx.x >> 7;
    float a = 0.f;
    for (int i = s0 + half; i < s1; i += 2) a += x[(size_t)cnodes[i] * HD + col];
    __shared__ float red[256];
    red[threadIdx.x] = a;
    __syncthreads();
    if (half == 0) {
        float s = red[col] + red[col + 128];
        atomicAdd(&pf[cl * HD + col], s);
    }
}
__global__ void k_pool_final(const float* __restrict__ pf, const int* __restrict__ ccount,
                             const bf16* __restrict__ tr, bf16* __restrict__ pooled) {
    int i = blockIdx.x * 256 + threadIdx.x;
    int cl = i >> 7;
    int c = ccount[cl];
    float v = pf[i] / (float)(c > 1 ? c : 1) * bf2f(tr[cl]);
    pooled[i] = f2bf(v);
}

// ===== deg-0 fixup (runs AFTER k_fused, which skips deg-0 rows) =====
// upd = leaky(x@Wu_x + pooled[cc]@Wu_p + bu)   (aggr term is exactly 0)
__global__ void k_fix(const bf16* __restrict__ xb, const bf16* __restrict__ pooled,
                      const bf16* __restrict__ Wu, const bf16* __restrict__ bu,
                      const int* __restrict__ cc, float* __restrict__ x,
                      const int* __restrict__ n0list, const int* __restrict__ n0cnt,
                      bf16* __restrict__ xbo, const int* __restrict__ flags,
                      void* __restrict__ out, int last) {
    __shared__ float xv[128], pv[128];
    int cnt = min(*n0cnt, MAXFIX);
    int col = threadIdx.x;
    int fp32out = flags[0];
    for (int j = blockIdx.x; j < cnt; j += gridDim.x) {
        int v = n0list[j];
        xv[col] = bf2f(xb[(size_t)v * HD + col]);
        pv[col] = bf2f(pooled[cc[v] * HD + col]);
        __syncthreads();
        float acc = bf2f(bu[col]);
        for (int k = 0; k < 128; k++)
            acc += xv[k] * bf2f(Wu[k * 128 + col]) + pv[k] * bf2f(Wu[(256 + k) * 128 + col]);
        float u = acc > 0.f ? acc : 0.01f * acc;
        size_t idx = (size_t)v * HD + col;
        float nv = x[idx] + u;
        if (last) {
            if (fp32out) ((float*)out)[idx] = nv;
            else ((bf16*)out)[idx] = f2bf(nv);
        } else {
            x[idx] = nv;
            xbo[idx] = f2bf(nv);
        }
        __syncthreads();
    }
}

// ================= per-layer fused update: ONE K=384 GEMM, no LDS, no barriers ====
// upd = leaky( x@W1 + m@W2 + pooled[cc]@W3 + b' );  x += upd. deg-0 rows are
// SKIPPED (k_fix handles them exactly). Swapped MFMA operands -> transposed D ->
// float4 epilogue.
__global__ __launch_bounds__(256) void k_fused(
    const bf16* __restrict__ xb, const bf16* __restrict__ mb, const bf16* __restrict__ pooled,
    const bf16* __restrict__ Wc, const float* __restrict__ bc,
    const int* __restrict__ cc, const int* __restrict__ deg,
    float* __restrict__ x, bf16* __restrict__ xbo,
    const int* __restrict__ flags, void* __restrict__ out, int last) {
    int tid = threadIdx.x;
    int r0 = blockIdx.x * 64;
    int wave = tid >> 6, lane = tid & 63, quad = lane >> 4, nidx = lane & 15;
    int colbase = wave * 32;

    int arow[4];
#pragma unroll
    for (int rt = 0; rt < 4; rt++) {
        int gr = r0 + rt * 16 + nidx;
        arow[rt] = (gr < N_NODES) ? gr : (N_NODES - 1);
    }
    int cci[4], dv[4];
#pragma unroll
    for (int rt = 0; rt < 4; rt++) {
        cci[rt] = cc[arow[rt]];
        dv[rt] = deg[arow[rt]];
    }

    f4v acc[4][2];
#pragma unroll
    for (int rt = 0; rt < 4; rt++)
#pragma unroll
        for (int ct = 0; ct < 2; ct++) acc[rt][ct] = (f4v){0.f, 0.f, 0.f, 0.f};

#pragma unroll
    for (int s = 0; s < 12; s++) {
        int k0 = s * 32;
        s8v bfrag[4];
        if (s < 4) {
#pragma unroll
            for (int rt = 0; rt < 4; rt++)
                bfrag[rt] = *(const s8v*)((const short*)xb + (size_t)arow[rt] * HD + k0 + quad * 8);
        } else if (s < 8) {
            int kk = k0 - 128;
#pragma unroll
            for (int rt = 0; rt < 4; rt++)
                bfrag[rt] = *(const s8v*)((const short*)mb + (size_t)arow[rt] * HD + kk + quad * 8);
        } else {
            int kk = k0 - 256;
#pragma unroll
            for (int rt = 0; rt < 4; rt++)
                bfrag[rt] = *(const s8v*)((const short*)pooled + (size_t)cci[rt] * HD + kk + quad * 8);
        }
#pragma unroll
        for (int ct = 0; ct < 2; ct++) {
            s8v wfr = *(const s8v*)((const short*)Wc + (colbase + ct * 16 + nidx) * 384 + k0 + quad * 8);
#pragma unroll
            for (int rt = 0; rt < 4; rt++)
                acc[rt][ct] = __builtin_amdgcn_mfma_f32_16x16x32_bf16(wfr, bfrag[rt], acc[rt][ct], 0, 0, 0);
        }
    }

    int fp32out = flags[0];
#pragma unroll
    for (int rt = 0; rt < 4; rt++) {
        int gr = r0 + rt * 16 + nidx;
        if (gr < N_NODES && dv[rt] > 0) {
#pragma unroll
            for (int ct = 0; ct < 2; ct++) {
                int wc0 = colbase + ct * 16 + quad * 4;
                f4v bv = *(const f4v*)(bc + wc0);
                size_t idx = (size_t)gr * HD + wc0;
                f4v xo = *(const f4v*)(x + idx);
                f4v nv;
#pragma unroll
                for (int r = 0; r < 4; r++) {
                    float v = acc[rt][ct][r] + bv[r];
                    v = (v > 0.f) ? v : 0.01f * v;
                    nv[r] = xo[r] + v;
                }
                if (last) {
                    if (fp32out) {
                        *(f4v*)((float*)out + idx) = nv;
                    } else {
                        s4v ob;
#pragma unroll
                        for (int r = 0; r < 4; r++) { bf16 h = f2bf(nv[r]); ob[r] = *(short*)&h; }
                        *(s4v*)((short*)out + idx) = ob;
                    }
                } else {
                    *(f4v*)(x + idx) = nv;
                    s4v ob;
#pragma unroll
                    for (int r = 0; r < 4; r++) { bf16 h = f2bf(nv[r]); ob[r] = *(short*)&h; }
                    *(s4v*)((short*)xbo + idx) = ob;
                }
            }
        }
    }
}

extern "C" void kernel_launch(void* const* d_in, const int* in_sizes, int n_in,
                              void* d_out, int out_size, void* d_ws, size_t ws_size,
                              hipStream_t stream) {
    const void* cf_r = d_in[0];
    const void* slf_r = d_in[1];
    const void* z_r = d_in[2];
    const void* tr_r = d_in[3];
    const void* Wenc_r = d_in[4];
    const void* benc_r = d_in[5];
    const void* Wm_r = d_in[6];
    const void* bm_r = d_in[7];
    const void* Wu_r = d_in[8];
    const void* bu_r = d_in[9];
    const int* e_r = (const int*)d_in[10];
    const int* cc_r = (const int*)d_in[11];

    char* w = (char*)d_ws;
    auto alloc = [&](size_t bytes) -> char* {
        char* p = w;
        w += (bytes + 63) & ~(size_t)63;
        return p;
    };
    float* x = (float*)alloc((size_t)N_NODES * HD * 4);
    bf16* xb0 = (bf16*)alloc((size_t)N_NODES * HD * 2);
    bf16* xb1 = (bf16*)alloc((size_t)N_NODES * HD * 2);
    bf16* mb = (bf16*)alloc((size_t)N_NODES * HD * 2);
    bf16* xin = (bf16*)alloc((size_t)N_NODES * 64 * 2);
    bf16* Wc = (bf16*)alloc(128 * 384 * 2);
    float* bc = (float*)alloc(128 * 4);
    bf16* Wet = (bf16*)alloc(128 * 64 * 2);
    float* bcenc = (float*)alloc(128 * 4);
    float* pooledf = (float*)alloc(NBC * HD * 4);
    bf16* pooled = (bf16*)alloc(NBC * HD * 2);
    int* deg = (int*)alloc(N_NODES * 4);
    int* rowptr = (int*)alloc((N_NODES + 1) * 4);
    int* cursor = (int*)alloc(N_NODES * 4);
    int* colx = (int*)alloc(N_EDGES * 4);
    int* ccount = (int*)alloc(NBC * 4);
    int* coff = (int*)alloc((NBC + 1) * 4);
    int* ccur = (int*)alloc(NBC * 4);
    int* cnodes = (int*)alloc(N_NODES * 4);
    int* flags = (int*)alloc(64);
    int* bsum = (int*)alloc(SCAN_B * 4);
    int* boff = (int*)alloc(SCAN_B * 4);
    int* n0list = (int*)alloc(MAXFIX * 4);
    int* n0cnt = (int*)alloc(64);
    bf16* trc = (bf16*)alloc(384 * 2);
    bf16* Wencc = (bf16*)alloc(6144 * 2);
    bf16* bencc = (bf16*)alloc(128 * 2);
    bf16* Wmc = (bf16*)alloc(32768 * 2);
    bf16* bmc = (bf16*)alloc(128 * 2);
    bf16* Wuc = (bf16*)alloc(49152 * 2);
    bf16* buc = (bf16*)alloc(128 * 2);
    int* ec = (int*)alloc(2 * N_EDGES * 4);
    int* ccc = (int*)alloc(N_NODES * 4);

    // dtype detection + canonical conversion (xin zeroed first for pad cols)
    k_detect<<<1, 64, 0, stream>>>((const unsigned short*)Wenc_r, e_r, flags);
    hipMemsetAsync(xin, 0, (size_t)N_NODES * 64 * 2, stream);
    k_cvt_all<<<C10, 256, 0, stream>>>(flags, cf_r, slf_r, z_r, tr_r, Wenc_r, benc_r,
                                       Wm_r, bm_r, Wu_r, bu_r,
                                       xin, trc, Wencc, bencc, Wmc, bmc, Wuc, buc);
    k_cvt_ints<<<B_E + 391, 256, 0, stream>>>(flags, e_r, cc_r, ec, ccc);

    // composed weights + MFMA encoder
    k_prep2<<<225, 256, 0, stream>>>(Wmc, Wuc, bmc, buc, Wencc, bencc, Wc, bc, Wet, bcenc);
    k_encoder_mfma<<<(N_NODES + 63) / 64, 256, 0, stream>>>(xin, Wet, bcenc, x, xb0);

    // CSR build
    hipMemsetAsync(deg, 0, (size_t)N_NODES * 4, stream);
    hipMemsetAsync(ccount, 0, (size_t)NBC * 4, stream);
    hipMemsetAsync(n0cnt, 0, 64, stream);
    k_count_edges<<<(N_EDGES + 255) / 256, 256, 0, stream>>>(ec, deg);
    k_count_nodes<<<(N_NODES + 255) / 256, 256, 0, stream>>>(ccc, ccount);
    k_scan_a<<<SCAN_B, 1024, 0, stream>>>(deg, rowptr, bsum);
    k_scan_b<<<1, 128, 0, stream>>>(bsum, boff, rowptr);
    k_scan_c<<<SCAN_B, 1024, 0, stream>>>(rowptr, cursor, boff);
    k_scan_clusters<<<1, 512, 0, stream>>>(ccount, coff, ccur);
    k_fill_edges<<<(N_EDGES + 255) / 256, 256, 0, stream>>>(ec, cursor, colx);
    k_fill_nodes<<<(N_NODES + 255) / 256, 256, 0, stream>>>(ccc, ccur, cnodes);
    k_list0<<<(N_NODES + 255) / 256, 256, 0, stream>>>(deg, n0list, n0cnt);

    bf16* xbufs[2] = {xb0, xb1};
    for (int layer = 0; layer < 3; layer++) {
        bf16* xbi = xbufs[layer & 1];
        bf16* xbo = xbufs[(layer + 1) & 1];
        int last = (layer == 2);
        hipMemsetAsync(pooledf, 0, (size_t)NBC * HD * 4, stream);
        k_aggregate<<<N_NODES / 4, 256, 0, stream>>>(xbi, rowptr, colx, mb);
        k_pool_partial<<<NBC * 4, 256, 0, stream>>>(x, coff, cnodes, pooledf);
        k_pool_final<<<NBC * HD / 256, 256, 0, stream>>>(pooledf, ccount, trc, pooled);
        k_fused<<<(N_NODES + 63) / 64, 256, 0, stream>>>(xbi, mb, pooled, Wc, bc,
                                                         ccc, deg, x, xbo, flags, d_out, last);
        k_fix<<<256, 128, 0, stream>>>(xbi, pooled, Wuc, buc, ccc, x,
                                       n0list, n0cnt, xbo, flags, d_out, last);
    }
}

// Round 7
// 766.753 us; speedup vs baseline: 1.1914x; 1.0223x over previous
//
#include <hip/hip_runtime.h>
#include <hip/hip_bf16.h>

#define N_NODES 100000
#define N_EDGES 600000
#define HD 128
#define NBC 384
#define SCAN_B 98   // ceil(N_NODES/1024)
#define MAXFIX 4096 // cap on deg-0 fixup list (E[count]~250 for Poisson(6))

typedef __attribute__((ext_vector_type(8))) short s8v;
typedef __attribute__((ext_vector_type(4))) short s4v;
typedef __attribute__((ext_vector_type(4))) float f4v;
typedef __hip_bfloat16 bf16;

static __device__ __forceinline__ float bf2f(bf16 v) { return __bfloat162float(v); }
static __device__ __forceinline__ bf16 f2bf(float v) { return __float2bfloat16(v); }
static __device__ __forceinline__ float sh2f(short s) { bf16 h = *(bf16*)&s; return bf2f(h); }

// ================= dtype detection =================
__global__ void k_detect(const unsigned short* __restrict__ wraw,
                         const int* __restrict__ eraw, int* __restrict__ flags) {
    if (threadIdx.x == 0 && blockIdx.x == 0) {
        int fp32 = 0;
        for (int i = 0; i < 1024; i++) {
            unsigned int u = ((unsigned int)wraw[i]) << 16;
            float f = fabsf(__uint_as_float(u));
            if (!(f <= 1e4f)) fp32 = 1;  // catches huge AND NaN
        }
        int i64 = (eraw[1] == 0 && eraw[3] == 0 && eraw[5] == 0 && eraw[7] == 0) ? 1 : 0;
        flags[0] = fp32;
        flags[1] = i64;
    }
}

// ========== canonical conversion; cf/slf/z packed into xin[N][64] (bf16) ==========
// xin cols: 0-14 cf, 15 slf, 16-47 z, 48-63 zero (memset'd before this kernel)
#define B_CF 5860
#define C1 (B_CF)
#define C2 (C1 + 391)
#define C3 (C2 + 12500)
#define C4 (C3 + 2)
#define C5 (C4 + 24)
#define C6 (C5 + 1)
#define C7 (C6 + 128)
#define C8 (C7 + 1)
#define C9 (C8 + 192)
#define C10 (C9 + 1)
__global__ void k_cvt_all(const int* __restrict__ flags,
                          const void* s0, const void* s1, const void* s2, const void* s3,
                          const void* s4, const void* s5, const void* s6, const void* s7,
                          const void* s8, const void* s9,
                          bf16* __restrict__ xin,
                          bf16* d3, bf16* d4, bf16* d5, bf16* d6, bf16* d7,
                          bf16* d8, bf16* d9) {
    int b = blockIdx.x;
    int fp32 = flags[0];
    if (b < C3) {
        const void* src; int n, lb, range;
        if (b < C1)      { src = s0; n = 1500000; lb = b;      range = 0; }
        else if (b < C2) { src = s1; n = 100000;  lb = b - C1; range = 1; }
        else             { src = s2; n = 3200000; lb = b - C2; range = 2; }
        int i = lb * 256 + threadIdx.x;
        if (i < n) {
            float v = fp32 ? ((const float*)src)[i] : bf2f(((const bf16*)src)[i]);
            size_t di;
            if (range == 0)      { int node = i / 15; di = (size_t)node * 64 + (i - node * 15); }
            else if (range == 1) { di = (size_t)i * 64 + 15; }
            else                 { di = (size_t)(i >> 5) * 64 + 16 + (i & 31); }
            xin[di] = f2bf(v);
        }
        return;
    }
    const void* src; bf16* dst; int n, lb;
    if (b < C4)       { src = s3; dst = d3; n = 384;   lb = b - C3; }
    else if (b < C5)  { src = s4; dst = d4; n = 6144;  lb = b - C4; }
    else if (b < C6)  { src = s5; dst = d5; n = 128;   lb = b - C5; }
    else if (b < C7)  { src = s6; dst = d6; n = 32768; lb = b - C6; }
    else if (b < C8)  { src = s7; dst = d7; n = 128;   lb = b - C7; }
    else if (b < C9)  { src = s8; dst = d8; n = 49152; lb = b - C8; }
    else              { src = s9; dst = d9; n = 128;   lb = b - C9; }
    int i = lb * 256 + threadIdx.x;
    if (i < n) {
        if (fp32) dst[i] = f2bf(((const float*)src)[i]);
        else      dst[i] = ((const bf16*)src)[i];
    }
}

#define B_E 4688
__global__ void k_cvt_ints(const int* __restrict__ flags, const int* __restrict__ e,
                           const int* __restrict__ cc, int* __restrict__ ec,
                           int* __restrict__ ccc) {
    int i64 = flags[1];
    int b = blockIdx.x;
    if (b < B_E) {
        int i = b * 256 + threadIdx.x;
        if (i < 2 * N_EDGES) ec[i] = i64 ? e[2 * i] : e[i];
    } else {
        int i = (b - B_E) * 256 + threadIdx.x;
        if (i < N_NODES) ccc[i] = i64 ? cc[2 * i] : cc[i];
    }
}

// ====== composed-weight prep ======
__global__ void k_prep2(const bf16* __restrict__ Wm, const bf16* __restrict__ Wu,
                        const bf16* __restrict__ bm, const bf16* __restrict__ bu,
                        const bf16* __restrict__ Wenc, const bf16* __restrict__ benc,
                        bf16* __restrict__ Wc, float* __restrict__ bc,
                        bf16* __restrict__ Wet, float* __restrict__ bcenc) {
    int b = blockIdx.x;
    if (b < 192) {
        int i = b * 256 + threadIdx.x;  // < 49152
        int w = i / 384, kk = i - w * 384;
        float acc = 0.f;
        if (kk < 128) {
            acc = bf2f(Wu[kk * 128 + w]);
            for (int j = 0; j < 128; j++)
                acc += bf2f(Wm[kk * 128 + j]) * bf2f(Wu[(128 + j) * 128 + w]);
        } else if (kk < 256) {
            int kp = kk - 128;
            for (int j = 0; j < 128; j++)
                acc += bf2f(Wm[(128 + kp) * 128 + j]) * bf2f(Wu[(128 + j) * 128 + w]);
        } else {
            acc = bf2f(Wu[kk * 128 + w]);
        }
        Wc[w * 384 + kk] = f2bf(acc);
    } else if (b < 224) {
        int i = (b - 192) * 256 + threadIdx.x;  // < 8192
        int w = i >> 6, kk = i & 63;
        bf16 zero; { float zf = 0.f; zero = f2bf(zf); }
        Wet[i] = (kk < 48) ? Wenc[kk * 128 + w] : zero;
    } else {
        int t = threadIdx.x;
        if (t < 128) {
            float acc = bf2f(bu[t]);
            for (int j = 0; j < 128; j++)
                acc += bf2f(bm[j]) * bf2f(Wu[(128 + j) * 128 + t]);
            bc[t] = acc;
        } else {
            bcenc[t - 128] = bf2f(benc[t - 128]);
        }
    }
}

// ================= MFMA encoder: xb = bf16( xin[N,64] @ Wet^T + benc ) ==========
__global__ __launch_bounds__(256, 4) void k_encoder_mfma(
    const bf16* __restrict__ xin, const bf16* __restrict__ Wet,
    const float* __restrict__ bcenc, bf16* __restrict__ xb) {
    int tid = threadIdx.x;
    int r0 = blockIdx.x * 64;
    int wave = tid >> 6, lane = tid & 63, quad = lane >> 4, nidx = lane & 15;
    int colbase = wave * 32;

    int arow[4];
#pragma unroll
    for (int rt = 0; rt < 4; rt++) {
        int gr = r0 + rt * 16 + nidx;
        arow[rt] = (gr < N_NODES) ? gr : (N_NODES - 1);
    }
    f4v acc[4][2];
#pragma unroll
    for (int rt = 0; rt < 4; rt++)
#pragma unroll
        for (int ct = 0; ct < 2; ct++) acc[rt][ct] = (f4v){0.f, 0.f, 0.f, 0.f};

#pragma unroll
    for (int s = 0; s < 2; s++) {
        int k0 = s * 32;
        s8v bfrag[4];
#pragma unroll
        for (int rt = 0; rt < 4; rt++)
            bfrag[rt] = *(const s8v*)((const short*)xin + (size_t)arow[rt] * 64 + k0 + quad * 8);
#pragma unroll
        for (int ct = 0; ct < 2; ct++) {
            s8v wfr = *(const s8v*)((const short*)Wet + (colbase + ct * 16 + nidx) * 64 + k0 + quad * 8);
#pragma unroll
            for (int rt = 0; rt < 4; rt++)
                acc[rt][ct] = __builtin_amdgcn_mfma_f32_16x16x32_bf16(wfr, bfrag[rt], acc[rt][ct], 0, 0, 0);
        }
    }
#pragma unroll
    for (int rt = 0; rt < 4; rt++) {
        int gr = r0 + rt * 16 + nidx;
        if (gr < N_NODES) {
#pragma unroll
            for (int ct = 0; ct < 2; ct++) {
                int wc0 = colbase + ct * 16 + quad * 4;
                f4v bv = *(const f4v*)(bcenc + wc0);
                size_t idx = (size_t)gr * HD + wc0;
                s4v ob;
#pragma unroll
                for (int r = 0; r < 4; r++) {
                    float nv = acc[rt][ct][r] + bv[r];
                    bf16 h = f2bf(nv);
                    ob[r] = *(short*)&h;
                }
                *(s4v*)((short*)xb + idx) = ob;
            }
        }
    }
}

// ================= CSR build =================
__global__ void k_count_edges(const int* __restrict__ e, int* __restrict__ deg) {
    int i = blockIdx.x * 256 + threadIdx.x;
    if (i < N_EDGES) atomicAdd(&deg[e[N_EDGES + i]], 1);
}
__global__ void k_count_nodes(const int* __restrict__ cc, int* __restrict__ ccount) {
    int i = blockIdx.x * 256 + threadIdx.x;
    if (i < N_NODES) atomicAdd(&ccount[cc[i]], 1);
}

__global__ void k_scan_a(const int* __restrict__ deg, int* __restrict__ rowptr,
                         int* __restrict__ bsum) {
    __shared__ int sd[1024];
    int t = threadIdx.x;
    int i = blockIdx.x * 1024 + t;
    int v = (i < N_NODES) ? deg[i] : 0;
    sd[t] = v;
    __syncthreads();
#pragma unroll
    for (int off = 1; off < 1024; off <<= 1) {
        int u = (t >= off) ? sd[t - off] : 0;
        __syncthreads();
        sd[t] += u;
        __syncthreads();
    }
    if (i < N_NODES) rowptr[i] = sd[t] - v;
    if (t == 1023) bsum[blockIdx.x] = sd[t];
}
__global__ void k_scan_b(const int* __restrict__ bsum, int* __restrict__ boff,
                         int* __restrict__ rowptr) {
    __shared__ int sd[128];
    int t = threadIdx.x;
    int v = (t < SCAN_B) ? bsum[t] : 0;
    sd[t] = v;
    __syncthreads();
#pragma unroll
    for (int off = 1; off < 128; off <<= 1) {
        int u = (t >= off) ? sd[t - off] : 0;
        __syncthreads();
        sd[t] += u;
        __syncthreads();
    }
    if (t < SCAN_B) boff[t] = sd[t] - v;
    if (t == 0) rowptr[N_NODES] = N_EDGES;
}
__global__ void k_scan_c(int* __restrict__ rowptr, int* __restrict__ cursor,
                         const int* __restrict__ boff) {
    int i = blockIdx.x * 1024 + threadIdx.x;
    if (i < N_NODES) {
        int r = rowptr[i] + boff[blockIdx.x];
        rowptr[i] = r;
        cursor[i] = r;
    }
}

__global__ void k_scan_clusters(const int* __restrict__ ccount, int* __restrict__ coff,
                                int* __restrict__ ccur) {
    __shared__ int sd[512];
    int t = threadIdx.x;
    sd[t] = (t < NBC) ? ccount[t] : 0;
    __syncthreads();
    for (int off = 1; off < 512; off <<= 1) {
        int v = (t >= off) ? sd[t - off] : 0;
        __syncthreads();
        sd[t] += v;
        __syncthreads();
    }
    if (t < NBC) {
        int ex = (t == 0) ? 0 : sd[t - 1];
        coff[t] = ex;
        ccur[t] = ex;
        if (t == NBC - 1) coff[NBC] = sd[t];
    }
}

__global__ void k_fill_edges(const int* __restrict__ e, int* __restrict__ cursor,
                             int* __restrict__ colx) {
    int i = blockIdx.x * 256 + threadIdx.x;
    if (i < N_EDGES) {
        int d = e[N_EDGES + i];
        int p = atomicAdd(&cursor[d], 1);
        colx[p] = e[i];
    }
}
__global__ void k_fill_nodes(const int* __restrict__ cc, int* __restrict__ ccur,
                             int* __restrict__ cnodes) {
    int i = blockIdx.x * 256 + threadIdx.x;
    if (i < N_NODES) {
        int p = atomicAdd(&ccur[cc[i]], 1);
        cnodes[p] = i;
    }
}

__global__ void k_list0(const int* __restrict__ deg, int* __restrict__ n0list,
                        int* __restrict__ n0cnt) {
    int i = blockIdx.x * 256 + threadIdx.x;
    if (i < N_NODES && deg[i] == 0) {
        int p = atomicAdd(n0cnt, 1);
        if (p < MAXFIX) n0list[p] = i;
    }
}

// ================= per-layer: mean of x[src] over incoming edges =================
__global__ void k_aggregate(const bf16* __restrict__ xb, const int* __restrict__ rowptr,
                            const int* __restrict__ colx, bf16* __restrict__ mb) {
    int wave = threadIdx.x >> 6, lane = threadIdx.x & 63;
    int node = blockIdx.x * 4 + wave;
    if (node >= N_NODES) return;
    int lo = rowptr[node], hi = rowptr[node + 1];
    float a0 = 0.f, a1 = 0.f;
    int j = lo;
    while (j + 2 <= hi) {
        int s0 = colx[j], s1 = colx[j + 1];
        __hip_bfloat162 v0 = *((const __hip_bfloat162*)(xb + (size_t)s0 * HD) + lane);
        __hip_bfloat162 v1 = *((const __hip_bfloat162*)(xb + (size_t)s1 * HD) + lane);
        a0 += bf2f(v0.x) + bf2f(v1.x);
        a1 += bf2f(v0.y) + bf2f(v1.y);
        j += 2;
    }
    if (j < hi) {
        int s0 = colx[j];
        __hip_bfloat162 v0 = *((const __hip_bfloat162*)(xb + (size_t)s0 * HD) + lane);
        a0 += bf2f(v0.x);
        a1 += bf2f(v0.y);
    }
    int d = hi - lo;
    float inv = 1.0f / (float)(d > 1 ? d : 1);
    __hip_bfloat162 o;
    o.x = f2bf(a0 * inv);
    o.y = f2bf(a1 * inv);
    *((__hip_bfloat162*)(mb + (size_t)node * HD) + lane) = o;
}

// ================= per-layer: cluster pooling (bf16 in, fp32 accumulate) ========
__global__ void k_pool_partial(const bf16* __restrict__ xb, const int* __restrict__ coff,
                               const int* __restrict__ cnodes, float* __restrict__ pf) {
    int cl = blockIdx.x >> 2, seg = blockIdx.x & 3;
    int lo = coff[cl], hi = coff[cl + 1];
    int cnt = hi - lo;
    int per = (cnt + 3) >> 2;
    int s0 = lo + seg * per;
    int s1 = min(s0 + per, hi);
    int col = threadIdx.x & 127, half = threadIdx.x >> 7;
    float a = 0.f;
    for (int i = s0 + half; i < s1; i += 2) a += bf2f(xb[(size_t)cnodes[i] * HD + col]);
    __shared__ float red[256];
    red[threadIdx.x] = a;
    __syncthreads();
    if (half == 0) {
        float s = red[col] + red[col + 128];
        atomicAdd(&pf[cl * HD + col], s);
    }
}
__global__ void k_pool_final(const float* __restrict__ pf, const int* __restrict__ ccount,
                             const bf16* __restrict__ tr, bf16* __restrict__ pooled) {
    int i = blockIdx.x * 256 + threadIdx.x;
    int cl = i >> 7;
    int c = ccount[cl];
    float v = pf[i] / (float)(c > 1 ? c : 1) * bf2f(tr[cl]);
    pooled[i] = f2bf(v);
}

// ===== deg-0 fixup (runs AFTER k_fused, which skips deg-0 rows) =====
__global__ void k_fix(const bf16* __restrict__ xb, const bf16* __restrict__ pooled,
                      const bf16* __restrict__ Wu, const bf16* __restrict__ bu,
                      const int* __restrict__ cc,
                      const int* __restrict__ n0list, const int* __restrict__ n0cnt,
                      bf16* __restrict__ xbo, const int* __restrict__ flags,
                      void* __restrict__ out, int last) {
    __shared__ float xv[128], pv[128];
    int cnt = min(*n0cnt, MAXFIX);
    int col = threadIdx.x;
    int fp32out = flags[0];
    for (int j = blockIdx.x; j < cnt; j += gridDim.x) {
        int v = n0list[j];
        xv[col] = bf2f(xb[(size_t)v * HD + col]);
        pv[col] = bf2f(pooled[cc[v] * HD + col]);
        __syncthreads();
        float acc = bf2f(bu[col]);
        for (int k = 0; k < 128; k++)
            acc += xv[k] * bf2f(Wu[k * 128 + col]) + pv[k] * bf2f(Wu[(256 + k) * 128 + col]);
        float u = acc > 0.f ? acc : 0.01f * acc;
        size_t idx = (size_t)v * HD + col;
        float nv = xv[col] + u;
        if (last) {
            if (fp32out) ((float*)out)[idx] = nv;
            else ((bf16*)out)[idx] = f2bf(nv);
        } else {
            xbo[idx] = f2bf(nv);
        }
        __syncthreads();
    }
}

// ================= per-layer fused update: ONE K=384 GEMM, no LDS, no barriers ====
// upd = leaky( x@W1 + m@W2 + pooled[cc]@W3 + b' );  xbo = bf16(xb + upd).
// bf16 residual stream (fp32 master removed: absmax headroom 4x, saves 100MB/layer).
__global__ __launch_bounds__(256, 4) void k_fused(
    const bf16* __restrict__ xb, const bf16* __restrict__ mb, const bf16* __restrict__ pooled,
    const bf16* __restrict__ Wc, const float* __restrict__ bc,
    const int* __restrict__ cc, const int* __restrict__ deg,
    bf16* __restrict__ xbo,
    const int* __restrict__ flags, void* __restrict__ out, int last) {
    int tid = threadIdx.x;
    int r0 = blockIdx.x * 64;
    int wave = tid >> 6, lane = tid & 63, quad = lane >> 4, nidx = lane & 15;
    int colbase = wave * 32;

    int arow[4];
#pragma unroll
    for (int rt = 0; rt < 4; rt++) {
        int gr = r0 + rt * 16 + nidx;
        arow[rt] = (gr < N_NODES) ? gr : (N_NODES - 1);
    }
    int cci[4], dv[4];
#pragma unroll
    for (int rt = 0; rt < 4; rt++) {
        cci[rt] = cc[arow[rt]];
        dv[rt] = deg[arow[rt]];
    }

    f4v acc[4][2];
#pragma unroll
    for (int rt = 0; rt < 4; rt++)
#pragma unroll
        for (int ct = 0; ct < 2; ct++) acc[rt][ct] = (f4v){0.f, 0.f, 0.f, 0.f};

#pragma unroll
    for (int s = 0; s < 12; s++) {
        int k0 = s * 32;
        s8v bfrag[4];
        if (s < 4) {
#pragma unroll
            for (int rt = 0; rt < 4; rt++)
                bfrag[rt] = *(const s8v*)((const short*)xb + (size_t)arow[rt] * HD + k0 + quad * 8);
        } else if (s < 8) {
            int kk = k0 - 128;
#pragma unroll
            for (int rt = 0; rt < 4; rt++)
                bfrag[rt] = *(const s8v*)((const short*)mb + (size_t)arow[rt] * HD + kk + quad * 8);
        } else {
            int kk = k0 - 256;
#pragma unroll
            for (int rt = 0; rt < 4; rt++)
                bfrag[rt] = *(const s8v*)((const short*)pooled + (size_t)cci[rt] * HD + kk + quad * 8);
        }
#pragma unroll
        for (int ct = 0; ct < 2; ct++) {
            s8v wfr = *(const s8v*)((const short*)Wc + (colbase + ct * 16 + nidx) * 384 + k0 + quad * 8);
#pragma unroll
            for (int rt = 0; rt < 4; rt++)
                acc[rt][ct] = __builtin_amdgcn_mfma_f32_16x16x32_bf16(wfr, bfrag[rt], acc[rt][ct], 0, 0, 0);
        }
    }

    int fp32out = flags[0];
#pragma unroll
    for (int rt = 0; rt < 4; rt++) {
        int gr = r0 + rt * 16 + nidx;
        if (gr < N_NODES && dv[rt] > 0) {
#pragma unroll
            for (int ct = 0; ct < 2; ct++) {
                int wc0 = colbase + ct * 16 + quad * 4;
                f4v bv = *(const f4v*)(bc + wc0);
                size_t idx = (size_t)gr * HD + wc0;
                s4v xo4 = *(const s4v*)((const short*)xb + idx);  // bf16 residual base
                f4v nv;
#pragma unroll
                for (int r = 0; r < 4; r++) {
                    float v = acc[rt][ct][r] + bv[r];
                    v = (v > 0.f) ? v : 0.01f * v;
                    nv[r] = sh2f(xo4[r]) + v;
                }
                if (last) {
                    if (fp32out) {
                        *(f4v*)((float*)out + idx) = nv;
                    } else {
                        s4v ob;
#pragma unroll
                        for (int r = 0; r < 4; r++) { bf16 h = f2bf(nv[r]); ob[r] = *(short*)&h; }
                        *(s4v*)((short*)out + idx) = ob;
                    }
                } else {
                    s4v ob;
#pragma unroll
                    for (int r = 0; r < 4; r++) { bf16 h = f2bf(nv[r]); ob[r] = *(short*)&h; }
                    *(s4v*)((short*)xbo + idx) = ob;
                }
            }
        }
    }
}

extern "C" void kernel_launch(void* const* d_in, const int* in_sizes, int n_in,
                              void* d_out, int out_size, void* d_ws, size_t ws_size,
                              hipStream_t stream) {
    const void* cf_r = d_in[0];
    const void* slf_r = d_in[1];
    const void* z_r = d_in[2];
    const void* tr_r = d_in[3];
    const void* Wenc_r = d_in[4];
    const void* benc_r = d_in[5];
    const void* Wm_r = d_in[6];
    const void* bm_r = d_in[7];
    const void* Wu_r = d_in[8];
    const void* bu_r = d_in[9];
    const int* e_r = (const int*)d_in[10];
    const int* cc_r = (const int*)d_in[11];

    char* w = (char*)d_ws;
    auto alloc = [&](size_t bytes) -> char* {
        char* p = w;
        w += (bytes + 63) & ~(size_t)63;
        return p;
    };
    bf16* xb0 = (bf16*)alloc((size_t)N_NODES * HD * 2);
    bf16* xb1 = (bf16*)alloc((size_t)N_NODES * HD * 2);
    bf16* mb = (bf16*)alloc((size_t)N_NODES * HD * 2);
    bf16* xin = (bf16*)alloc((size_t)N_NODES * 64 * 2);
    bf16* Wc = (bf16*)alloc(128 * 384 * 2);
    float* bc = (float*)alloc(128 * 4);
    bf16* Wet = (bf16*)alloc(128 * 64 * 2);
    float* bcenc = (float*)alloc(128 * 4);
    float* pooledf = (float*)alloc(NBC * HD * 4);
    bf16* pooled = (bf16*)alloc(NBC * HD * 2);
    int* deg = (int*)alloc(N_NODES * 4);
    int* rowptr = (int*)alloc((N_NODES + 1) * 4);
    int* cursor = (int*)alloc(N_NODES * 4);
    int* colx = (int*)alloc(N_EDGES * 4);
    int* ccount = (int*)alloc(NBC * 4);
    int* coff = (int*)alloc((NBC + 1) * 4);
    int* ccur = (int*)alloc(NBC * 4);
    int* cnodes = (int*)alloc(N_NODES * 4);
    int* flags = (int*)alloc(64);
    int* bsum = (int*)alloc(SCAN_B * 4);
    int* boff = (int*)alloc(SCAN_B * 4);
    int* n0list = (int*)alloc(MAXFIX * 4);
    int* n0cnt = (int*)alloc(64);
    bf16* trc = (bf16*)alloc(384 * 2);
    bf16* Wencc = (bf16*)alloc(6144 * 2);
    bf16* bencc = (bf16*)alloc(128 * 2);
    bf16* Wmc = (bf16*)alloc(32768 * 2);
    bf16* bmc = (bf16*)alloc(128 * 2);
    bf16* Wuc = (bf16*)alloc(49152 * 2);
    bf16* buc = (bf16*)alloc(128 * 2);
    int* ec = (int*)alloc(2 * N_EDGES * 4);
    int* ccc = (int*)alloc(N_NODES * 4);

    // dtype detection + canonical conversion (xin zeroed first for pad cols)
    k_detect<<<1, 64, 0, stream>>>((const unsigned short*)Wenc_r, e_r, flags);
    hipMemsetAsync(xin, 0, (size_t)N_NODES * 64 * 2, stream);
    k_cvt_all<<<C10, 256, 0, stream>>>(flags, cf_r, slf_r, z_r, tr_r, Wenc_r, benc_r,
                                       Wm_r, bm_r, Wu_r, bu_r,
                                       xin, trc, Wencc, bencc, Wmc, bmc, Wuc, buc);
    k_cvt_ints<<<B_E + 391, 256, 0, stream>>>(flags, e_r, cc_r, ec, ccc);

    // composed weights + MFMA encoder
    k_prep2<<<225, 256, 0, stream>>>(Wmc, Wuc, bmc, buc, Wencc, bencc, Wc, bc, Wet, bcenc);
    k_encoder_mfma<<<(N_NODES + 63) / 64, 256, 0, stream>>>(xin, Wet, bcenc, xb0);

    // CSR build
    hipMemsetAsync(deg, 0, (size_t)N_NODES * 4, stream);
    hipMemsetAsync(ccount, 0, (size_t)NBC * 4, stream);
    hipMemsetAsync(n0cnt, 0, 64, stream);
    k_count_edges<<<(N_EDGES + 255) / 256, 256, 0, stream>>>(ec, deg);
    k_count_nodes<<<(N_NODES + 255) / 256, 256, 0, stream>>>(ccc, ccount);
    k_scan_a<<<SCAN_B, 1024, 0, stream>>>(deg, rowptr, bsum);
    k_scan_b<<<1, 128, 0, stream>>>(bsum, boff, rowptr);
    k_scan_c<<<SCAN_B, 1024, 0, stream>>>(rowptr, cursor, boff);
    k_scan_clusters<<<1, 512, 0, stream>>>(ccount, coff, ccur);
    k_fill_edges<<<(N_EDGES + 255) / 256, 256, 0, stream>>>(ec, cursor, colx);
    k_fill_nodes<<<(N_NODES + 255) / 256, 256, 0, stream>>>(ccc, ccur, cnodes);
    k_list0<<<(N_NODES + 255) / 256, 256, 0, stream>>>(deg, n0list, n0cnt);

    bf16* xbufs[2] = {xb0, xb1};
    for (int layer = 0; layer < 3; layer++) {
        bf16* xbi = xbufs[layer & 1];
        bf16* xbo = xbufs[(layer + 1) & 1];
        int last = (layer == 2);
        hipMemsetAsync(pooledf, 0, (size_t)NBC * HD * 4, stream);
        k_aggregate<<<N_NODES / 4, 256, 0, stream>>>(xbi, rowptr, colx, mb);
        k_pool_partial<<<NBC * 4, 256, 0, stream>>>(xbi, coff, cnodes, pooledf);
        k_pool_final<<<NBC * HD / 256, 256, 0, stream>>>(pooledf, ccount, trc, pooled);
        k_fused<<<(N_NODES + 63) / 64, 256, 0, stream>>>(xbi, mb, pooled, Wc, bc,
                                                         ccc, deg, xbo, flags, d_out, last);
        k_fix<<<256, 128, 0, stream>>>(xbi, pooled, Wuc, buc, ccc,
                                       n0list, n0cnt, xbo, flags, d_out, last);
    }
}

// Round 8
// 643.561 us; speedup vs baseline: 1.4194x; 1.1914x over previous
//
#include <hip/hip_runtime.h>
#include <hip/hip_bf16.h>

#define N_NODES 100000
#define N_EDGES 600000
#define HD 128
#define NBC 384
#define SCAN_B 98   // ceil(N_NODES/1024)
#define MAXFIX 4096 // cap on deg-0 fixup list (E[count]~250 for Poisson(6))
#define TILES ((N_NODES + 63) / 64)  // 1563
#define GRID_F 512  // persistent blocks for k_fused2 (2/CU)

typedef __attribute__((ext_vector_type(8))) short s8v;
typedef __attribute__((ext_vector_type(4))) short s4v;
typedef __attribute__((ext_vector_type(4))) float f4v;
typedef __hip_bfloat16 bf16;

static __device__ __forceinline__ float bf2f(bf16 v) { return __bfloat162float(v); }
static __device__ __forceinline__ bf16 f2bf(float v) { return __float2bfloat16(v); }
static __device__ __forceinline__ float sh2f(short s) { bf16 h = *(bf16*)&s; return bf2f(h); }

// async global->LDS, 16B per lane; lds dest = wave-uniform base + lane*16
static __device__ __forceinline__ void gl2lds16(const void* g, void* l) {
    __builtin_amdgcn_global_load_lds(
        (const __attribute__((address_space(1))) void*)g,
        (__attribute__((address_space(3))) void*)l, 16, 0, 0);
}

// ================= dtype detection =================
__global__ void k_detect(const unsigned short* __restrict__ wraw,
                         const int* __restrict__ eraw, int* __restrict__ flags) {
    if (threadIdx.x == 0 && blockIdx.x == 0) {
        int fp32 = 0;
        for (int i = 0; i < 1024; i++) {
            unsigned int u = ((unsigned int)wraw[i]) << 16;
            float f = fabsf(__uint_as_float(u));
            if (!(f <= 1e4f)) fp32 = 1;  // catches huge AND NaN
        }
        int i64 = (eraw[1] == 0 && eraw[3] == 0 && eraw[5] == 0 && eraw[7] == 0) ? 1 : 0;
        flags[0] = fp32;
        flags[1] = i64;
    }
}

// ========== canonical conversion; cf/slf/z packed into xin[N][64] (bf16) ==========
#define B_CF 5860
#define C1 (B_CF)
#define C2 (C1 + 391)
#define C3 (C2 + 12500)
#define C4 (C3 + 2)
#define C5 (C4 + 24)
#define C6 (C5 + 1)
#define C7 (C6 + 128)
#define C8 (C7 + 1)
#define C9 (C8 + 192)
#define C10 (C9 + 1)
__global__ void k_cvt_all(const int* __restrict__ flags,
                          const void* s0, const void* s1, const void* s2, const void* s3,
                          const void* s4, const void* s5, const void* s6, const void* s7,
                          const void* s8, const void* s9,
                          bf16* __restrict__ xin,
                          bf16* d3, bf16* d4, bf16* d5, bf16* d6, bf16* d7,
                          bf16* d8, bf16* d9) {
    int b = blockIdx.x;
    int fp32 = flags[0];
    if (b < C3) {
        const void* src; int n, lb, range;
        if (b < C1)      { src = s0; n = 1500000; lb = b;      range = 0; }
        else if (b < C2) { src = s1; n = 100000;  lb = b - C1; range = 1; }
        else             { src = s2; n = 3200000; lb = b - C2; range = 2; }
        int i = lb * 256 + threadIdx.x;
        if (i < n) {
            float v = fp32 ? ((const float*)src)[i] : bf2f(((const bf16*)src)[i]);
            size_t di;
            if (range == 0)      { int node = i / 15; di = (size_t)node * 64 + (i - node * 15); }
            else if (range == 1) { di = (size_t)i * 64 + 15; }
            else                 { di = (size_t)(i >> 5) * 64 + 16 + (i & 31); }
            xin[di] = f2bf(v);
        }
        return;
    }
    const void* src; bf16* dst; int n, lb;
    if (b < C4)       { src = s3; dst = d3; n = 384;   lb = b - C3; }
    else if (b < C5)  { src = s4; dst = d4; n = 6144;  lb = b - C4; }
    else if (b < C6)  { src = s5; dst = d5; n = 128;   lb = b - C5; }
    else if (b < C7)  { src = s6; dst = d6; n = 32768; lb = b - C6; }
    else if (b < C8)  { src = s7; dst = d7; n = 128;   lb = b - C7; }
    else if (b < C9)  { src = s8; dst = d8; n = 49152; lb = b - C8; }
    else              { src = s9; dst = d9; n = 128;   lb = b - C9; }
    int i = lb * 256 + threadIdx.x;
    if (i < n) {
        if (fp32) dst[i] = f2bf(((const float*)src)[i]);
        else      dst[i] = ((const bf16*)src)[i];
    }
}

#define B_E 4688
__global__ void k_cvt_ints(const int* __restrict__ flags, const int* __restrict__ e,
                           const int* __restrict__ cc, int* __restrict__ ec,
                           int* __restrict__ ccc) {
    int i64 = flags[1];
    int b = blockIdx.x;
    if (b < B_E) {
        int i = b * 256 + threadIdx.x;
        if (i < 2 * N_EDGES) ec[i] = i64 ? e[2 * i] : e[i];
    } else {
        int i = (b - B_E) * 256 + threadIdx.x;
        if (i < N_NODES) ccc[i] = i64 ? cc[2 * i] : cc[i];
    }
}

// ====== composed-weight prep ======
__global__ void k_prep2(const bf16* __restrict__ Wm, const bf16* __restrict__ Wu,
                        const bf16* __restrict__ bm, const bf16* __restrict__ bu,
                        const bf16* __restrict__ Wenc, const bf16* __restrict__ benc,
                        bf16* __restrict__ Wc, float* __restrict__ bc,
                        bf16* __restrict__ Wet, float* __restrict__ bcenc) {
    int b = blockIdx.x;
    if (b < 192) {
        int i = b * 256 + threadIdx.x;  // < 49152
        int w = i / 384, kk = i - w * 384;
        float acc = 0.f;
        if (kk < 128) {
            acc = bf2f(Wu[kk * 128 + w]);
            for (int j = 0; j < 128; j++)
                acc += bf2f(Wm[kk * 128 + j]) * bf2f(Wu[(128 + j) * 128 + w]);
        } else if (kk < 256) {
            int kp = kk - 128;
            for (int j = 0; j < 128; j++)
                acc += bf2f(Wm[(128 + kp) * 128 + j]) * bf2f(Wu[(128 + j) * 128 + w]);
        } else {
            acc = bf2f(Wu[kk * 128 + w]);
        }
        Wc[w * 384 + kk] = f2bf(acc);
    } else if (b < 224) {
        int i = (b - 192) * 256 + threadIdx.x;  // < 8192
        int w = i >> 6, kk = i & 63;
        bf16 zero; { float zf = 0.f; zero = f2bf(zf); }
        Wet[i] = (kk < 48) ? Wenc[kk * 128 + w] : zero;
    } else {
        int t = threadIdx.x;
        if (t < 128) {
            float acc = bf2f(bu[t]);
            for (int j = 0; j < 128; j++)
                acc += bf2f(bm[j]) * bf2f(Wu[(128 + j) * 128 + t]);
            bc[t] = acc;
        } else {
            bcenc[t - 128] = bf2f(benc[t - 128]);
        }
    }
}

// ================= MFMA encoder: xb = bf16( xin[N,64] @ Wet^T + benc ) ==========
__global__ __launch_bounds__(256, 4) void k_encoder_mfma(
    const bf16* __restrict__ xin, const bf16* __restrict__ Wet,
    const float* __restrict__ bcenc, bf16* __restrict__ xb) {
    int tid = threadIdx.x;
    int r0 = blockIdx.x * 64;
    int wave = tid >> 6, lane = tid & 63, quad = lane >> 4, nidx = lane & 15;
    int colbase = wave * 32;

    int arow[4];
#pragma unroll
    for (int rt = 0; rt < 4; rt++) {
        int gr = r0 + rt * 16 + nidx;
        arow[rt] = (gr < N_NODES) ? gr : (N_NODES - 1);
    }
    f4v acc[4][2];
#pragma unroll
    for (int rt = 0; rt < 4; rt++)
#pragma unroll
        for (int ct = 0; ct < 2; ct++) acc[rt][ct] = (f4v){0.f, 0.f, 0.f, 0.f};

#pragma unroll
    for (int s = 0; s < 2; s++) {
        int k0 = s * 32;
        s8v bfrag[4];
#pragma unroll
        for (int rt = 0; rt < 4; rt++)
            bfrag[rt] = *(const s8v*)((const short*)xin + (size_t)arow[rt] * 64 + k0 + quad * 8);
#pragma unroll
        for (int ct = 0; ct < 2; ct++) {
            s8v wfr = *(const s8v*)((const short*)Wet + (colbase + ct * 16 + nidx) * 64 + k0 + quad * 8);
#pragma unroll
            for (int rt = 0; rt < 4; rt++)
                acc[rt][ct] = __builtin_amdgcn_mfma_f32_16x16x32_bf16(wfr, bfrag[rt], acc[rt][ct], 0, 0, 0);
        }
    }
#pragma unroll
    for (int rt = 0; rt < 4; rt++) {
        int gr = r0 + rt * 16 + nidx;
        if (gr < N_NODES) {
#pragma unroll
            for (int ct = 0; ct < 2; ct++) {
                int wc0 = colbase + ct * 16 + quad * 4;
                f4v bv = *(const f4v*)(bcenc + wc0);
                size_t idx = (size_t)gr * HD + wc0;
                s4v ob;
#pragma unroll
                for (int r = 0; r < 4; r++) {
                    float nv = acc[rt][ct][r] + bv[r];
                    bf16 h = f2bf(nv);
                    ob[r] = *(short*)&h;
                }
                *(s4v*)((short*)xb + idx) = ob;
            }
        }
    }
}

// ================= CSR build =================
__global__ void k_count_edges(const int* __restrict__ e, int* __restrict__ deg) {
    int i = blockIdx.x * 256 + threadIdx.x;
    if (i < N_EDGES) atomicAdd(&deg[e[N_EDGES + i]], 1);
}
__global__ void k_count_nodes(const int* __restrict__ cc, int* __restrict__ ccount) {
    int i = blockIdx.x * 256 + threadIdx.x;
    if (i < N_NODES) atomicAdd(&ccount[cc[i]], 1);
}

__global__ void k_scan_a(const int* __restrict__ deg, int* __restrict__ rowptr,
                         int* __restrict__ bsum) {
    __shared__ int sd[1024];
    int t = threadIdx.x;
    int i = blockIdx.x * 1024 + t;
    int v = (i < N_NODES) ? deg[i] : 0;
    sd[t] = v;
    __syncthreads();
#pragma unroll
    for (int off = 1; off < 1024; off <<= 1) {
        int u = (t >= off) ? sd[t - off] : 0;
        __syncthreads();
        sd[t] += u;
        __syncthreads();
    }
    if (i < N_NODES) rowptr[i] = sd[t] - v;
    if (t == 1023) bsum[blockIdx.x] = sd[t];
}
__global__ void k_scan_b(const int* __restrict__ bsum, int* __restrict__ boff,
                         int* __restrict__ rowptr) {
    __shared__ int sd[128];
    int t = threadIdx.x;
    int v = (t < SCAN_B) ? bsum[t] : 0;
    sd[t] = v;
    __syncthreads();
#pragma unroll
    for (int off = 1; off < 128; off <<= 1) {
        int u = (t >= off) ? sd[t - off] : 0;
        __syncthreads();
        sd[t] += u;
        __syncthreads();
    }
    if (t < SCAN_B) boff[t] = sd[t] - v;
    if (t == 0) rowptr[N_NODES] = N_EDGES;
}
__global__ void k_scan_c(int* __restrict__ rowptr, int* __restrict__ cursor,
                         const int* __restrict__ boff) {
    int i = blockIdx.x * 1024 + threadIdx.x;
    if (i < N_NODES) {
        int r = rowptr[i] + boff[blockIdx.x];
        rowptr[i] = r;
        cursor[i] = r;
    }
}

__global__ void k_scan_clusters(const int* __restrict__ ccount, int* __restrict__ coff,
                                int* __restrict__ ccur) {
    __shared__ int sd[512];
    int t = threadIdx.x;
    sd[t] = (t < NBC) ? ccount[t] : 0;
    __syncthreads();
    for (int off = 1; off < 512; off <<= 1) {
        int v = (t >= off) ? sd[t - off] : 0;
        __syncthreads();
        sd[t] += v;
        __syncthreads();
    }
    if (t < NBC) {
        int ex = (t == 0) ? 0 : sd[t - 1];
        coff[t] = ex;
        ccur[t] = ex;
        if (t == NBC - 1) coff[NBC] = sd[t];
    }
}

__global__ void k_fill_edges(const int* __restrict__ e, int* __restrict__ cursor,
                             int* __restrict__ colx) {
    int i = blockIdx.x * 256 + threadIdx.x;
    if (i < N_EDGES) {
        int d = e[N_EDGES + i];
        int p = atomicAdd(&cursor[d], 1);
        colx[p] = e[i];
    }
}
__global__ void k_fill_nodes(const int* __restrict__ cc, int* __restrict__ ccur,
                             int* __restrict__ cnodes) {
    int i = blockIdx.x * 256 + threadIdx.x;
    if (i < N_NODES) {
        int p = atomicAdd(&ccur[cc[i]], 1);
        cnodes[p] = i;
    }
}

__global__ void k_list0(const int* __restrict__ deg, int* __restrict__ n0list,
                        int* __restrict__ n0cnt) {
    int i = blockIdx.x * 256 + threadIdx.x;
    if (i < N_NODES && deg[i] == 0) {
        int p = atomicAdd(n0cnt, 1);
        if (p < MAXFIX) n0list[p] = i;
    }
}

// ================= per-layer: mean of x[src] over incoming edges =================
__global__ void k_aggregate(const bf16* __restrict__ xb, const int* __restrict__ rowptr,
                            const int* __restrict__ colx, bf16* __restrict__ mb) {
    int wave = threadIdx.x >> 6, lane = threadIdx.x & 63;
    int node = blockIdx.x * 4 + wave;
    if (node >= N_NODES) return;
    int lo = rowptr[node], hi = rowptr[node + 1];
    float a0 = 0.f, a1 = 0.f;
    int j = lo;
    while (j + 2 <= hi) {
        int s0 = colx[j], s1 = colx[j + 1];
        __hip_bfloat162 v0 = *((const __hip_bfloat162*)(xb + (size_t)s0 * HD) + lane);
        __hip_bfloat162 v1 = *((const __hip_bfloat162*)(xb + (size_t)s1 * HD) + lane);
        a0 += bf2f(v0.x) + bf2f(v1.x);
        a1 += bf2f(v0.y) + bf2f(v1.y);
        j += 2;
    }
    if (j < hi) {
        int s0 = colx[j];
        __hip_bfloat162 v0 = *((const __hip_bfloat162*)(xb + (size_t)s0 * HD) + lane);
        a0 += bf2f(v0.x);
        a1 += bf2f(v0.y);
    }
    int d = hi - lo;
    float inv = 1.0f / (float)(d > 1 ? d : 1);
    __hip_bfloat162 o;
    o.x = f2bf(a0 * inv);
    o.y = f2bf(a1 * inv);
    *((__hip_bfloat162*)(mb + (size_t)node * HD) + lane) = o;
}

// ================= per-layer: cluster pooling (bf16 in, fp32 accumulate) ========
__global__ void k_pool_partial(const bf16* __restrict__ xb, const int* __restrict__ coff,
                               const int* __restrict__ cnodes, float* __restrict__ pf) {
    int cl = blockIdx.x >> 2, seg = blockIdx.x & 3;
    int lo = coff[cl], hi = coff[cl + 1];
    int cnt = hi - lo;
    int per = (cnt + 3) >> 2;
    int s0 = lo + seg * per;
    int s1 = min(s0 + per, hi);
    int col = threadIdx.x & 127, half = threadIdx.x >> 7;
    float a = 0.f;
    for (int i = s0 + half; i < s1; i += 2) a += bf2f(xb[(size_t)cnodes[i] * HD + col]);
    __shared__ float red[256];
    red[threadIdx.x] = a;
    __syncthreads();
    if (half == 0) {
        float s = red[col] + red[col + 128];
        atomicAdd(&pf[cl * HD + col], s);
    }
}
__global__ void k_pool_final(const float* __restrict__ pf, const int* __restrict__ ccount,
                             const bf16* __restrict__ tr, bf16* __restrict__ pooled) {
    int i = blockIdx.x * 256 + threadIdx.x;
    int cl = i >> 7;
    int c = ccount[cl];
    float v = pf[i] / (float)(c > 1 ? c : 1) * bf2f(tr[cl]);
    pooled[i] = f2bf(v);
}

// ===== deg-0 fixup (runs AFTER k_fused2, which skips deg-0 rows) =====
__global__ void k_fix(const bf16* __restrict__ xb, const bf16* __restrict__ pooled,
                      const bf16* __restrict__ Wu, const bf16* __restrict__ bu,
                      const int* __restrict__ cc,
                      const int* __restrict__ n0list, const int* __restrict__ n0cnt,
                      bf16* __restrict__ xbo, const int* __restrict__ flags,
                      void* __restrict__ out, int last) {
    __shared__ float xv[128], pv[128];
    int cnt = min(*n0cnt, MAXFIX);
    int col = threadIdx.x;
    int fp32out = flags[0];
    for (int j = blockIdx.x; j < cnt; j += gridDim.x) {
        int v = n0list[j];
        xv[col] = bf2f(xb[(size_t)v * HD + col]);
        pv[col] = bf2f(pooled[cc[v] * HD + col]);
        __syncthreads();
        float acc = bf2f(bu[col]);
        for (int k = 0; k < 128; k++)
            acc += xv[k] * bf2f(Wu[k * 128 + col]) + pv[k] * bf2f(Wu[(256 + k) * 128 + col]);
        float u = acc > 0.f ? acc : 0.01f * acc;
        size_t idx = (size_t)v * HD + col;
        float nv = xv[col] + u;
        if (last) {
            if (fp32out) ((float*)out)[idx] = nv;
            else ((bf16*)out)[idx] = f2bf(nv);
        } else {
            xbo[idx] = f2bf(nv);
        }
        __syncthreads();
    }
}

// ======== per-layer fused update v2: persistent blocks + LDS-staged A-tiles ======
// upd = leaky( [x|m|pooled[cc]] @ Wc + b' );  xbo = bf16(xb + upd).
// - 512 persistent blocks grid-stride over 1563 64-row tiles
// - xb/mb/pooled staged ONCE per block into LDS via global_load_lds (width 16),
//   XOR chunk-swizzle (slot = chunk ^ (row&15)) kills ds_read_b128 bank conflicts
// - weights held in REGISTERS (24 x s8v per lane, loaded once per block)
// - weight-col swizzle wcol(m)=colbase+(m>>2)*8+ct*4+(m&3) -> lane owns 8 consecutive
//   output cols -> single 16B store per rt; residual read from LDS (Lx)
__global__ __launch_bounds__(256, 2) void k_fused2(
    const bf16* __restrict__ xb, const bf16* __restrict__ mb, const bf16* __restrict__ pooled,
    const bf16* __restrict__ Wc, const float* __restrict__ bc,
    const int* __restrict__ cc, const int* __restrict__ deg,
    bf16* __restrict__ xbo, const int* __restrict__ flags,
    void* __restrict__ out, int last) {
    __shared__ short Lx[64 * 128];
    __shared__ short Lm[64 * 128];
    __shared__ short Lp[64 * 128];
    int tid = threadIdx.x;
    int wave = tid >> 6, lane = tid & 63, quad = lane >> 4, nidx = lane & 15;
    int colbase = wave * 32;
    int fp32out = flags[0];

    // weights -> registers (96 VGPRs): lane's A-row m=nidx maps to swizzled wcol
    s8v wfr[12][2];
#pragma unroll
    for (int ct = 0; ct < 2; ct++) {
        int wcol = colbase + ((nidx >> 2) << 3) + ct * 4 + (nidx & 3);
        const short* wrow = (const short*)Wc + (size_t)wcol * 384 + quad * 8;
#pragma unroll
        for (int s = 0; s < 12; s++) wfr[s][ct] = *(const s8v*)(wrow + s * 32);
    }
    int cb2 = colbase + quad * 8;          // lane's 8 consecutive output cols
    f4v bv0 = *(const f4v*)(bc + cb2);
    f4v bv1 = *(const f4v*)(bc + cb2 + 4);

    int srow = lane >> 4;   // staging: row within 4-row group
    int sc = lane & 15;     // staging: LDS slot

    for (int t = blockIdx.x; t < TILES; t += GRID_F) {
        int r0 = t * 64;
        // ---- stage tile (each wave: 4 instrs x 3 sources) ----
#pragma unroll
        for (int ii = 0; ii < 4; ii++) {
            int i = wave * 4 + ii;        // 0..15: 4-row group
            int lr = i * 4 + srow;        // local row 0..63
            int gr = r0 + lr;
            int grc = (gr < N_NODES) ? gr : (N_NODES - 1);
            int gc = sc ^ (lr & 15);      // swizzled source chunk
            gl2lds16((const short*)xb + (size_t)grc * HD + gc * 8, (char*)Lx + i * 1024);
            gl2lds16((const short*)mb + (size_t)grc * HD + gc * 8, (char*)Lm + i * 1024);
            int ci = cc[grc];
            gl2lds16((const short*)pooled + (size_t)ci * HD + gc * 8, (char*)Lp + i * 1024);
        }
        __syncthreads();  // drains global_load_lds (vmcnt) + barrier

        f4v acc[4][2];
#pragma unroll
        for (int rt = 0; rt < 4; rt++)
#pragma unroll
            for (int ct = 0; ct < 2; ct++) acc[rt][ct] = (f4v){0.f, 0.f, 0.f, 0.f};

#pragma unroll
        for (int s = 0; s < 12; s++) {
            const short* Ls = (s < 4) ? Lx : ((s < 8) ? Lm : Lp);
            int c = (s & 3) * 4 + quad;   // chunk within segment
            s8v bfrag[4];
#pragma unroll
            for (int rt = 0; rt < 4; rt++) {
                int row = rt * 16 + nidx;
                int slot = c ^ nidx;
                bfrag[rt] = *(const s8v*)(Ls + row * 128 + slot * 8);
            }
#pragma unroll
            for (int ct = 0; ct < 2; ct++)
#pragma unroll
                for (int rt = 0; rt < 4; rt++)
                    acc[rt][ct] = __builtin_amdgcn_mfma_f32_16x16x32_bf16(wfr[s][ct], bfrag[rt], acc[rt][ct], 0, 0, 0);
        }

        // ---- epilogue: lane holds cols cb2..cb2+7 of row gr ----
#pragma unroll
        for (int rt = 0; rt < 4; rt++) {
            int gr = r0 + rt * 16 + nidx;
            if (gr < N_NODES && deg[gr] > 0) {
                int row = rt * 16 + nidx;
                int slot = ((colbase >> 3) + quad) ^ nidx;  // chunk cb2/8, swizzled
                s8v xo = *(const s8v*)(Lx + row * 128 + slot * 8);
                size_t idx = (size_t)gr * HD + cb2;
                float nv[8];
#pragma unroll
                for (int r = 0; r < 4; r++) {
                    float v0 = acc[rt][0][r] + bv0[r];
                    v0 = (v0 > 0.f) ? v0 : 0.01f * v0;
                    nv[r] = sh2f(xo[r]) + v0;
                    float v1 = acc[rt][1][r] + bv1[r];
                    v1 = (v1 > 0.f) ? v1 : 0.01f * v1;
                    nv[4 + r] = sh2f(xo[4 + r]) + v1;
                }
                if (last) {
                    if (fp32out) {
                        f4v o0 = {nv[0], nv[1], nv[2], nv[3]};
                        f4v o1 = {nv[4], nv[5], nv[6], nv[7]};
                        *(f4v*)((float*)out + idx) = o0;
                        *(f4v*)((float*)out + idx + 4) = o1;
                    } else {
                        s8v ob;
#pragma unroll
                        for (int r = 0; r < 8; r++) { bf16 h = f2bf(nv[r]); ob[r] = *(short*)&h; }
                        *(s8v*)((short*)out + idx) = ob;
                    }
                } else {
                    s8v ob;
#pragma unroll
                    for (int r = 0; r < 8; r++) { bf16 h = f2bf(nv[r]); ob[r] = *(short*)&h; }
                    *(s8v*)((short*)xbo + idx) = ob;
                }
            }
        }
        __syncthreads();  // LDS reuse fence before next tile's staging
    }
}

extern "C" void kernel_launch(void* const* d_in, const int* in_sizes, int n_in,
                              void* d_out, int out_size, void* d_ws, size_t ws_size,
                              hipStream_t stream) {
    const void* cf_r = d_in[0];
    const void* slf_r = d_in[1];
    const void* z_r = d_in[2];
    const void* tr_r = d_in[3];
    const void* Wenc_r = d_in[4];
    const void* benc_r = d_in[5];
    const void* Wm_r = d_in[6];
    const void* bm_r = d_in[7];
    const void* Wu_r = d_in[8];
    const void* bu_r = d_in[9];
    const int* e_r = (const int*)d_in[10];
    const int* cc_r = (const int*)d_in[11];

    char* w = (char*)d_ws;
    auto alloc = [&](size_t bytes) -> char* {
        char* p = w;
        w += (bytes + 63) & ~(size_t)63;
        return p;
    };
    bf16* xb0 = (bf16*)alloc((size_t)N_NODES * HD * 2);
    bf16* xb1 = (bf16*)alloc((size_t)N_NODES * HD * 2);
    bf16* mb = (bf16*)alloc((size_t)N_NODES * HD * 2);
    bf16* xin = (bf16*)alloc((size_t)N_NODES * 64 * 2);
    bf16* Wc = (bf16*)alloc(128 * 384 * 2);
    float* bc = (float*)alloc(128 * 4);
    bf16* Wet = (bf16*)alloc(128 * 64 * 2);
    float* bcenc = (float*)alloc(128 * 4);
    float* pooledf = (float*)alloc(NBC * HD * 4);
    bf16* pooled = (bf16*)alloc(NBC * HD * 2);
    int* deg = (int*)alloc(N_NODES * 4);
    int* rowptr = (int*)alloc((N_NODES + 1) * 4);
    int* cursor = (int*)alloc(N_NODES * 4);
    int* colx = (int*)alloc(N_EDGES * 4);
    int* ccount = (int*)alloc(NBC * 4);
    int* coff = (int*)alloc((NBC + 1) * 4);
    int* ccur = (int*)alloc(NBC * 4);
    int* cnodes = (int*)alloc(N_NODES * 4);
    int* flags = (int*)alloc(64);
    int* bsum = (int*)alloc(SCAN_B * 4);
    int* boff = (int*)alloc(SCAN_B * 4);
    int* n0list = (int*)alloc(MAXFIX * 4);
    int* n0cnt = (int*)alloc(64);
    bf16* trc = (bf16*)alloc(384 * 2);
    bf16* Wencc = (bf16*)alloc(6144 * 2);
    bf16* bencc = (bf16*)alloc(128 * 2);
    bf16* Wmc = (bf16*)alloc(32768 * 2);
    bf16* bmc = (bf16*)alloc(128 * 2);
    bf16* Wuc = (bf16*)alloc(49152 * 2);
    bf16* buc = (bf16*)alloc(128 * 2);
    int* ec = (int*)alloc(2 * N_EDGES * 4);
    int* ccc = (int*)alloc(N_NODES * 4);

    // dtype detection + canonical conversion (xin zeroed first for pad cols)
    k_detect<<<1, 64, 0, stream>>>((const unsigned short*)Wenc_r, e_r, flags);
    hipMemsetAsync(xin, 0, (size_t)N_NODES * 64 * 2, stream);
    k_cvt_all<<<C10, 256, 0, stream>>>(flags, cf_r, slf_r, z_r, tr_r, Wenc_r, benc_r,
                                       Wm_r, bm_r, Wu_r, bu_r,
                                       xin, trc, Wencc, bencc, Wmc, bmc, Wuc, buc);
    k_cvt_ints<<<B_E + 391, 256, 0, stream>>>(flags, e_r, cc_r, ec, ccc);

    // composed weights + MFMA encoder
    k_prep2<<<225, 256, 0, stream>>>(Wmc, Wuc, bmc, buc, Wencc, bencc, Wc, bc, Wet, bcenc);
    k_encoder_mfma<<<(N_NODES + 63) / 64, 256, 0, stream>>>(xin, Wet, bcenc, xb0);

    // CSR build
    hipMemsetAsync(deg, 0, (size_t)N_NODES * 4, stream);
    hipMemsetAsync(ccount, 0, (size_t)NBC * 4, stream);
    hipMemsetAsync(n0cnt, 0, 64, stream);
    k_count_edges<<<(N_EDGES + 255) / 256, 256, 0, stream>>>(ec, deg);
    k_count_nodes<<<(N_NODES + 255) / 256, 256, 0, stream>>>(ccc, ccount);
    k_scan_a<<<SCAN_B, 1024, 0, stream>>>(deg, rowptr, bsum);
    k_scan_b<<<1, 128, 0, stream>>>(bsum, boff, rowptr);
    k_scan_c<<<SCAN_B, 1024, 0, stream>>>(rowptr, cursor, boff);
    k_scan_clusters<<<1, 512, 0, stream>>>(ccount, coff, ccur);
    k_fill_edges<<<(N_EDGES + 255) / 256, 256, 0, stream>>>(ec, cursor, colx);
    k_fill_nodes<<<(N_NODES + 255) / 256, 256, 0, stream>>>(ccc, ccur, cnodes);
    k_list0<<<(N_NODES + 255) / 256, 256, 0, stream>>>(deg, n0list, n0cnt);

    bf16* xbufs[2] = {xb0, xb1};
    for (int layer = 0; layer < 3; layer++) {
        bf16* xbi = xbufs[layer & 1];
        bf16* xbo = xbufs[(layer + 1) & 1];
        int last = (layer == 2);
        hipMemsetAsync(pooledf, 0, (size_t)NBC * HD * 4, stream);
        k_aggregate<<<N_NODES / 4, 256, 0, stream>>>(xbi, rowptr, colx, mb);
        k_pool_partial<<<NBC * 4, 256, 0, stream>>>(xbi, coff, cnodes, pooledf);
        k_pool_final<<<NBC * HD / 256, 256, 0, stream>>>(pooledf, ccount, trc, pooled);
        k_fused2<<<GRID_F, 256, 0, stream>>>(xbi, mb, pooled, Wc, bc,
                                             ccc, deg, xbo, flags, d_out, last);
        k_fix<<<256, 128, 0, stream>>>(xbi, pooled, Wuc, buc, ccc,
                                       n0list, n0cnt, xbo, flags, d_out, last);
    }
}

// Round 9
// 618.384 us; speedup vs baseline: 1.4772x; 1.0407x over previous
//
#include <hip/hip_runtime.h>
#include <hip/hip_bf16.h>

#define N_NODES 100000
#define N_EDGES 600000
#define HD 128
#define NBC 384
#define SCAN_B 98   // ceil(N_NODES/1024)
#define MAXFIX 4096 // cap on deg-0 fixup list (E[count]~250 for Poisson(6))
#define TILES ((N_NODES + 63) / 64)  // 1563
#define GRID_F 512  // persistent blocks for k_fused2 (2/CU)

typedef __attribute__((ext_vector_type(8))) short s8v;
typedef __attribute__((ext_vector_type(4))) short s4v;
typedef __attribute__((ext_vector_type(4))) float f4v;
typedef __hip_bfloat16 bf16;

static __device__ __forceinline__ float bf2f(bf16 v) { return __bfloat162float(v); }
static __device__ __forceinline__ bf16 f2bf(float v) { return __float2bfloat16(v); }
static __device__ __forceinline__ float sh2f(short s) { bf16 h = *(bf16*)&s; return bf2f(h); }

// async global->LDS, 16B per lane; lds dest = wave-uniform base + lane*16
static __device__ __forceinline__ void gl2lds16(const void* g, void* l) {
    __builtin_amdgcn_global_load_lds(
        (const __attribute__((address_space(1))) void*)g,
        (__attribute__((address_space(3))) void*)l, 16, 0, 0);
}

// ================= dtype detection =================
__global__ void k_detect(const unsigned short* __restrict__ wraw,
                         const int* __restrict__ eraw, int* __restrict__ flags) {
    if (threadIdx.x == 0 && blockIdx.x == 0) {
        int fp32 = 0;
        for (int i = 0; i < 1024; i++) {
            unsigned int u = ((unsigned int)wraw[i]) << 16;
            float f = fabsf(__uint_as_float(u));
            if (!(f <= 1e4f)) fp32 = 1;  // catches huge AND NaN
        }
        int i64 = (eraw[1] == 0 && eraw[3] == 0 && eraw[5] == 0 && eraw[7] == 0) ? 1 : 0;
        flags[0] = fp32;
        flags[1] = i64;
    }
}

// ========== canonical conversion; cf/slf/z packed into xin[N][64] (bf16) ==========
#define B_CF 5860
#define C1 (B_CF)
#define C2 (C1 + 391)
#define C3 (C2 + 12500)
#define C4 (C3 + 2)
#define C5 (C4 + 24)
#define C6 (C5 + 1)
#define C7 (C6 + 128)
#define C8 (C7 + 1)
#define C9 (C8 + 192)
#define C10 (C9 + 1)
__global__ void k_cvt_all(const int* __restrict__ flags,
                          const void* s0, const void* s1, const void* s2, const void* s3,
                          const void* s4, const void* s5, const void* s6, const void* s7,
                          const void* s8, const void* s9,
                          bf16* __restrict__ xin,
                          bf16* d3, bf16* d4, bf16* d5, bf16* d6, bf16* d7,
                          bf16* d8, bf16* d9) {
    int b = blockIdx.x;
    int fp32 = flags[0];
    if (b < C3) {
        const void* src; int n, lb, range;
        if (b < C1)      { src = s0; n = 1500000; lb = b;      range = 0; }
        else if (b < C2) { src = s1; n = 100000;  lb = b - C1; range = 1; }
        else             { src = s2; n = 3200000; lb = b - C2; range = 2; }
        int i = lb * 256 + threadIdx.x;
        if (i < n) {
            float v = fp32 ? ((const float*)src)[i] : bf2f(((const bf16*)src)[i]);
            size_t di;
            if (range == 0)      { int node = i / 15; di = (size_t)node * 64 + (i - node * 15); }
            else if (range == 1) { di = (size_t)i * 64 + 15; }
            else                 { di = (size_t)(i >> 5) * 64 + 16 + (i & 31); }
            xin[di] = f2bf(v);
        }
        return;
    }
    const void* src; bf16* dst; int n, lb;
    if (b < C4)       { src = s3; dst = d3; n = 384;   lb = b - C3; }
    else if (b < C5)  { src = s4; dst = d4; n = 6144;  lb = b - C4; }
    else if (b < C6)  { src = s5; dst = d5; n = 128;   lb = b - C5; }
    else if (b < C7)  { src = s6; dst = d6; n = 32768; lb = b - C6; }
    else if (b < C8)  { src = s7; dst = d7; n = 128;   lb = b - C7; }
    else if (b < C9)  { src = s8; dst = d8; n = 49152; lb = b - C8; }
    else              { src = s9; dst = d9; n = 128;   lb = b - C9; }
    int i = lb * 256 + threadIdx.x;
    if (i < n) {
        if (fp32) dst[i] = f2bf(((const float*)src)[i]);
        else      dst[i] = ((const bf16*)src)[i];
    }
}

#define B_E 4688
__global__ void k_cvt_ints(const int* __restrict__ flags, const int* __restrict__ e,
                           const int* __restrict__ cc, int* __restrict__ ec,
                           int* __restrict__ ccc) {
    int i64 = flags[1];
    int b = blockIdx.x;
    if (b < B_E) {
        int i = b * 256 + threadIdx.x;
        if (i < 2 * N_EDGES) ec[i] = i64 ? e[2 * i] : e[i];
    } else {
        int i = (b - B_E) * 256 + threadIdx.x;
        if (i < N_NODES) ccc[i] = i64 ? cc[2 * i] : cc[i];
    }
}

// ====== composed-weight prep ======
__global__ void k_prep2(const bf16* __restrict__ Wm, const bf16* __restrict__ Wu,
                        const bf16* __restrict__ bm, const bf16* __restrict__ bu,
                        const bf16* __restrict__ Wenc, const bf16* __restrict__ benc,
                        bf16* __restrict__ Wc, float* __restrict__ bc,
                        bf16* __restrict__ Wet, float* __restrict__ bcenc) {
    int b = blockIdx.x;
    if (b < 192) {
        int i = b * 256 + threadIdx.x;  // < 49152
        int w = i / 384, kk = i - w * 384;
        float acc = 0.f;
        if (kk < 128) {
            acc = bf2f(Wu[kk * 128 + w]);
            for (int j = 0; j < 128; j++)
                acc += bf2f(Wm[kk * 128 + j]) * bf2f(Wu[(128 + j) * 128 + w]);
        } else if (kk < 256) {
            int kp = kk - 128;
            for (int j = 0; j < 128; j++)
                acc += bf2f(Wm[(128 + kp) * 128 + j]) * bf2f(Wu[(128 + j) * 128 + w]);
        } else {
            acc = bf2f(Wu[kk * 128 + w]);
        }
        Wc[w * 384 + kk] = f2bf(acc);
    } else if (b < 224) {
        int i = (b - 192) * 256 + threadIdx.x;  // < 8192
        int w = i >> 6, kk = i & 63;
        bf16 zero; { float zf = 0.f; zero = f2bf(zf); }
        Wet[i] = (kk < 48) ? Wenc[kk * 128 + w] : zero;
    } else {
        int t = threadIdx.x;
        if (t < 128) {
            float acc = bf2f(bu[t]);
            for (int j = 0; j < 128; j++)
                acc += bf2f(bm[j]) * bf2f(Wu[(128 + j) * 128 + t]);
            bc[t] = acc;
        } else {
            bcenc[t - 128] = bf2f(benc[t - 128]);
        }
    }
}

// ================= MFMA encoder: xb = bf16( xin[N,64] @ Wet^T + benc ) ==========
__global__ __launch_bounds__(256, 4) void k_encoder_mfma(
    const bf16* __restrict__ xin, const bf16* __restrict__ Wet,
    const float* __restrict__ bcenc, bf16* __restrict__ xb) {
    int tid = threadIdx.x;
    int r0 = blockIdx.x * 64;
    int wave = tid >> 6, lane = tid & 63, quad = lane >> 4, nidx = lane & 15;
    int colbase = wave * 32;

    int arow[4];
#pragma unroll
    for (int rt = 0; rt < 4; rt++) {
        int gr = r0 + rt * 16 + nidx;
        arow[rt] = (gr < N_NODES) ? gr : (N_NODES - 1);
    }
    f4v acc[4][2];
#pragma unroll
    for (int rt = 0; rt < 4; rt++)
#pragma unroll
        for (int ct = 0; ct < 2; ct++) acc[rt][ct] = (f4v){0.f, 0.f, 0.f, 0.f};

#pragma unroll
    for (int s = 0; s < 2; s++) {
        int k0 = s * 32;
        s8v bfrag[4];
#pragma unroll
        for (int rt = 0; rt < 4; rt++)
            bfrag[rt] = *(const s8v*)((const short*)xin + (size_t)arow[rt] * 64 + k0 + quad * 8);
#pragma unroll
        for (int ct = 0; ct < 2; ct++) {
            s8v wfr = *(const s8v*)((const short*)Wet + (colbase + ct * 16 + nidx) * 64 + k0 + quad * 8);
#pragma unroll
            for (int rt = 0; rt < 4; rt++)
                acc[rt][ct] = __builtin_amdgcn_mfma_f32_16x16x32_bf16(wfr, bfrag[rt], acc[rt][ct], 0, 0, 0);
        }
    }
#pragma unroll
    for (int rt = 0; rt < 4; rt++) {
        int gr = r0 + rt * 16 + nidx;
        if (gr < N_NODES) {
#pragma unroll
            for (int ct = 0; ct < 2; ct++) {
                int wc0 = colbase + ct * 16 + quad * 4;
                f4v bv = *(const f4v*)(bcenc + wc0);
                size_t idx = (size_t)gr * HD + wc0;
                s4v ob;
#pragma unroll
                for (int r = 0; r < 4; r++) {
                    float nv = acc[rt][ct][r] + bv[r];
                    bf16 h = f2bf(nv);
                    ob[r] = *(short*)&h;
                }
                *(s4v*)((short*)xb + idx) = ob;
            }
        }
    }
}

// ================= CSR build =================
__global__ void k_count_edges(const int* __restrict__ e, int* __restrict__ deg) {
    int i = blockIdx.x * 256 + threadIdx.x;
    if (i < N_EDGES) atomicAdd(&deg[e[N_EDGES + i]], 1);
}
__global__ void k_count_nodes(const int* __restrict__ cc, int* __restrict__ ccount) {
    int i = blockIdx.x * 256 + threadIdx.x;
    if (i < N_NODES) atomicAdd(&ccount[cc[i]], 1);
}

__global__ void k_scan_a(const int* __restrict__ deg, int* __restrict__ rowptr,
                         int* __restrict__ bsum) {
    __shared__ int sd[1024];
    int t = threadIdx.x;
    int i = blockIdx.x * 1024 + t;
    int v = (i < N_NODES) ? deg[i] : 0;
    sd[t] = v;
    __syncthreads();
#pragma unroll
    for (int off = 1; off < 1024; off <<= 1) {
        int u = (t >= off) ? sd[t - off] : 0;
        __syncthreads();
        sd[t] += u;
        __syncthreads();
    }
    if (i < N_NODES) rowptr[i] = sd[t] - v;
    if (t == 1023) bsum[blockIdx.x] = sd[t];
}
__global__ void k_scan_b(const int* __restrict__ bsum, int* __restrict__ boff,
                         int* __restrict__ rowptr) {
    __shared__ int sd[128];
    int t = threadIdx.x;
    int v = (t < SCAN_B) ? bsum[t] : 0;
    sd[t] = v;
    __syncthreads();
#pragma unroll
    for (int off = 1; off < 128; off <<= 1) {
        int u = (t >= off) ? sd[t - off] : 0;
        __syncthreads();
        sd[t] += u;
        __syncthreads();
    }
    if (t < SCAN_B) boff[t] = sd[t] - v;
    if (t == 0) rowptr[N_NODES] = N_EDGES;
}
__global__ void k_scan_c(int* __restrict__ rowptr, int* __restrict__ cursor,
                         const int* __restrict__ boff) {
    int i = blockIdx.x * 1024 + threadIdx.x;
    if (i < N_NODES) {
        int r = rowptr[i] + boff[blockIdx.x];
        rowptr[i] = r;
        cursor[i] = r;
    }
}

__global__ void k_scan_clusters(const int* __restrict__ ccount, int* __restrict__ coff,
                                int* __restrict__ ccur) {
    __shared__ int sd[512];
    int t = threadIdx.x;
    sd[t] = (t < NBC) ? ccount[t] : 0;
    __syncthreads();
    for (int off = 1; off < 512; off <<= 1) {
        int v = (t >= off) ? sd[t - off] : 0;
        __syncthreads();
        sd[t] += v;
        __syncthreads();
    }
    if (t < NBC) {
        int ex = (t == 0) ? 0 : sd[t - 1];
        coff[t] = ex;
        ccur[t] = ex;
        if (t == NBC - 1) coff[NBC] = sd[t];
    }
}

__global__ void k_fill_edges(const int* __restrict__ e, int* __restrict__ cursor,
                             int* __restrict__ colx) {
    int i = blockIdx.x * 256 + threadIdx.x;
    if (i < N_EDGES) {
        int d = e[N_EDGES + i];
        int p = atomicAdd(&cursor[d], 1);
        colx[p] = e[i];
    }
}
__global__ void k_fill_nodes(const int* __restrict__ cc, int* __restrict__ ccur,
                             int* __restrict__ cnodes) {
    int i = blockIdx.x * 256 + threadIdx.x;
    if (i < N_NODES) {
        int p = atomicAdd(&ccur[cc[i]], 1);
        cnodes[p] = i;
    }
}

__global__ void k_list0(const int* __restrict__ deg, int* __restrict__ n0list,
                        int* __restrict__ n0cnt) {
    int i = blockIdx.x * 256 + threadIdx.x;
    if (i < N_NODES && deg[i] == 0) {
        int p = atomicAdd(n0cnt, 1);
        if (p < MAXFIX) n0list[p] = i;
    }
}

// ============ per-layer: mean of x[src] over incoming edges (v2) ============
// Wave split into two 32-lane halves; each half owns alternate edges; each lane
// loads 8B (4 bf16) -> one wave64 instr fetches TWO 256B edge-rows. 2-wide unroll
// puts 4 edge-rows in flight. Halves combined via shfl_down(32); lanes 0-31 store
// 8B each (256B coalesced row).
__global__ void k_aggregate(const bf16* __restrict__ xb, const int* __restrict__ rowptr,
                            const int* __restrict__ colx, bf16* __restrict__ mb) {
    int wave = threadIdx.x >> 6, lane = threadIdx.x & 63;
    int node = blockIdx.x * 4 + wave;
    if (node >= N_NODES) return;
    int half = lane >> 5;   // 0: even-offset edges, 1: odd
    int l = lane & 31;      // column group: cols l*4 .. l*4+3
    int lo = rowptr[node], hi = rowptr[node + 1];
    float a0 = 0.f, a1 = 0.f, a2 = 0.f, a3 = 0.f;
    int j = lo + half;
    while (j + 2 < hi) {  // edges j and j+2 both valid
        int s0 = colx[j], s1 = colx[j + 2];
        s4v v0 = *(const s4v*)((const short*)xb + (size_t)s0 * HD + l * 4);
        s4v v1 = *(const s4v*)((const short*)xb + (size_t)s1 * HD + l * 4);
        a0 += sh2f(v0[0]) + sh2f(v1[0]);
        a1 += sh2f(v0[1]) + sh2f(v1[1]);
        a2 += sh2f(v0[2]) + sh2f(v1[2]);
        a3 += sh2f(v0[3]) + sh2f(v1[3]);
        j += 4;
    }
    if (j < hi) {
        int s0 = colx[j];
        s4v v0 = *(const s4v*)((const short*)xb + (size_t)s0 * HD + l * 4);
        a0 += sh2f(v0[0]);
        a1 += sh2f(v0[1]);
        a2 += sh2f(v0[2]);
        a3 += sh2f(v0[3]);
    }
    // combine halves: lanes 0-31 add lanes 32-63's partials
    a0 += __shfl_down(a0, 32);
    a1 += __shfl_down(a1, 32);
    a2 += __shfl_down(a2, 32);
    a3 += __shfl_down(a3, 32);
    if (half == 0) {
        int d = hi - lo;
        float inv = 1.0f / (float)(d > 1 ? d : 1);
        s4v o;
        bf16 h0 = f2bf(a0 * inv); o[0] = *(short*)&h0;
        bf16 h1 = f2bf(a1 * inv); o[1] = *(short*)&h1;
        bf16 h2 = f2bf(a2 * inv); o[2] = *(short*)&h2;
        bf16 h3 = f2bf(a3 * inv); o[3] = *(short*)&h3;
        *(s4v*)((short*)mb + (size_t)node * HD + l * 4) = o;
    }
}

// ================= per-layer: cluster pooling (bf16 in, fp32 accumulate) ========
__global__ void k_pool_partial(const bf16* __restrict__ xb, const int* __restrict__ coff,
                               const int* __restrict__ cnodes, float* __restrict__ pf) {
    int cl = blockIdx.x >> 2, seg = blockIdx.x & 3;
    int lo = coff[cl], hi = coff[cl + 1];
    int cnt = hi - lo;
    int per = (cnt + 3) >> 2;
    int s0 = lo + seg * per;
    int s1 = min(s0 + per, hi);
    int col = threadIdx.x & 127, half = threadIdx.x >> 7;
    float a = 0.f;
    for (int i = s0 + half; i < s1; i += 2) a += bf2f(xb[(size_t)cnodes[i] * HD + col]);
    __shared__ float red[256];
    red[threadIdx.x] = a;
    __syncthreads();
    if (half == 0) {
        float s = red[col] + red[col + 128];
        atomicAdd(&pf[cl * HD + col], s);
    }
}
__global__ void k_pool_final(const float* __restrict__ pf, const int* __restrict__ ccount,
                             const bf16* __restrict__ tr, bf16* __restrict__ pooled) {
    int i = blockIdx.x * 256 + threadIdx.x;
    int cl = i >> 7;
    int c = ccount[cl];
    float v = pf[i] / (float)(c > 1 ? c : 1) * bf2f(tr[cl]);
    pooled[i] = f2bf(v);
}

// ===== deg-0 fixup (runs AFTER k_fused2, which skips deg-0 rows) =====
__global__ void k_fix(const bf16* __restrict__ xb, const bf16* __restrict__ pooled,
                      const bf16* __restrict__ Wu, const bf16* __restrict__ bu,
                      const int* __restrict__ cc,
                      const int* __restrict__ n0list, const int* __restrict__ n0cnt,
                      bf16* __restrict__ xbo, const int* __restrict__ flags,
                      void* __restrict__ out, int last) {
    __shared__ float xv[128], pv[128];
    int cnt = min(*n0cnt, MAXFIX);
    int col = threadIdx.x;
    int fp32out = flags[0];
    for (int j = blockIdx.x; j < cnt; j += gridDim.x) {
        int v = n0list[j];
        xv[col] = bf2f(xb[(size_t)v * HD + col]);
        pv[col] = bf2f(pooled[cc[v] * HD + col]);
        __syncthreads();
        float acc = bf2f(bu[col]);
        for (int k = 0; k < 128; k++)
            acc += xv[k] * bf2f(Wu[k * 128 + col]) + pv[k] * bf2f(Wu[(256 + k) * 128 + col]);
        float u = acc > 0.f ? acc : 0.01f * acc;
        size_t idx = (size_t)v * HD + col;
        float nv = xv[col] + u;
        if (last) {
            if (fp32out) ((float*)out)[idx] = nv;
            else ((bf16*)out)[idx] = f2bf(nv);
        } else {
            xbo[idx] = f2bf(nv);
        }
        __syncthreads();
    }
}

// ======== per-layer fused update v2: persistent blocks + LDS-staged A-tiles ======
__global__ __launch_bounds__(256, 2) void k_fused2(
    const bf16* __restrict__ xb, const bf16* __restrict__ mb, const bf16* __restrict__ pooled,
    const bf16* __restrict__ Wc, const float* __restrict__ bc,
    const int* __restrict__ cc, const int* __restrict__ deg,
    bf16* __restrict__ xbo, const int* __restrict__ flags,
    void* __restrict__ out, int last) {
    __shared__ short Lx[64 * 128];
    __shared__ short Lm[64 * 128];
    __shared__ short Lp[64 * 128];
    int tid = threadIdx.x;
    int wave = tid >> 6, lane = tid & 63, quad = lane >> 4, nidx = lane & 15;
    int colbase = wave * 32;
    int fp32out = flags[0];

    s8v wfr[12][2];
#pragma unroll
    for (int ct = 0; ct < 2; ct++) {
        int wcol = colbase + ((nidx >> 2) << 3) + ct * 4 + (nidx & 3);
        const short* wrow = (const short*)Wc + (size_t)wcol * 384 + quad * 8;
#pragma unroll
        for (int s = 0; s < 12; s++) wfr[s][ct] = *(const s8v*)(wrow + s * 32);
    }
    int cb2 = colbase + quad * 8;
    f4v bv0 = *(const f4v*)(bc + cb2);
    f4v bv1 = *(const f4v*)(bc + cb2 + 4);

    int srow = lane >> 4;
    int sc = lane & 15;

    for (int t = blockIdx.x; t < TILES; t += GRID_F) {
        int r0 = t * 64;
#pragma unroll
        for (int ii = 0; ii < 4; ii++) {
            int i = wave * 4 + ii;
            int lr = i * 4 + srow;
            int gr = r0 + lr;
            int grc = (gr < N_NODES) ? gr : (N_NODES - 1);
            int gc = sc ^ (lr & 15);
            gl2lds16((const short*)xb + (size_t)grc * HD + gc * 8, (char*)Lx + i * 1024);
            gl2lds16((const short*)mb + (size_t)grc * HD + gc * 8, (char*)Lm + i * 1024);
            int ci = cc[grc];
            gl2lds16((const short*)pooled + (size_t)ci * HD + gc * 8, (char*)Lp + i * 1024);
        }
        __syncthreads();

        f4v acc[4][2];
#pragma unroll
        for (int rt = 0; rt < 4; rt++)
#pragma unroll
            for (int ct = 0; ct < 2; ct++) acc[rt][ct] = (f4v){0.f, 0.f, 0.f, 0.f};

#pragma unroll
        for (int s = 0; s < 12; s++) {
            const short* Ls = (s < 4) ? Lx : ((s < 8) ? Lm : Lp);
            int c = (s & 3) * 4 + quad;
            s8v bfrag[4];
#pragma unroll
            for (int rt = 0; rt < 4; rt++) {
                int row = rt * 16 + nidx;
                int slot = c ^ nidx;
                bfrag[rt] = *(const s8v*)(Ls + row * 128 + slot * 8);
            }
#pragma unroll
            for (int ct = 0; ct < 2; ct++)
#pragma unroll
                for (int rt = 0; rt < 4; rt++)
                    acc[rt][ct] = __builtin_amdgcn_mfma_f32_16x16x32_bf16(wfr[s][ct], bfrag[rt], acc[rt][ct], 0, 0, 0);
        }

#pragma unroll
        for (int rt = 0; rt < 4; rt++) {
            int gr = r0 + rt * 16 + nidx;
            if (gr < N_NODES && deg[gr] > 0) {
                int row = rt * 16 + nidx;
                int slot = ((colbase >> 3) + quad) ^ nidx;
                s8v xo = *(const s8v*)(Lx + row * 128 + slot * 8);
                size_t idx = (size_t)gr * HD + cb2;
                float nv[8];
#pragma unroll
                for (int r = 0; r < 4; r++) {
                    float v0 = acc[rt][0][r] + bv0[r];
                    v0 = (v0 > 0.f) ? v0 : 0.01f * v0;
                    nv[r] = sh2f(xo[r]) + v0;
                    float v1 = acc[rt][1][r] + bv1[r];
                    v1 = (v1 > 0.f) ? v1 : 0.01f * v1;
                    nv[4 + r] = sh2f(xo[4 + r]) + v1;
                }
                if (last) {
                    if (fp32out) {
                        f4v o0 = {nv[0], nv[1], nv[2], nv[3]};
                        f4v o1 = {nv[4], nv[5], nv[6], nv[7]};
                        *(f4v*)((float*)out + idx) = o0;
                        *(f4v*)((float*)out + idx + 4) = o1;
                    } else {
                        s8v ob;
#pragma unroll
                        for (int r = 0; r < 8; r++) { bf16 h = f2bf(nv[r]); ob[r] = *(short*)&h; }
                        *(s8v*)((short*)out + idx) = ob;
                    }
                } else {
                    s8v ob;
#pragma unroll
                    for (int r = 0; r < 8; r++) { bf16 h = f2bf(nv[r]); ob[r] = *(short*)&h; }
                    *(s8v*)((short*)xbo + idx) = ob;
                }
            }
        }
        __syncthreads();
    }
}

extern "C" void kernel_launch(void* const* d_in, const int* in_sizes, int n_in,
                              void* d_out, int out_size, void* d_ws, size_t ws_size,
                              hipStream_t stream) {
    const void* cf_r = d_in[0];
    const void* slf_r = d_in[1];
    const void* z_r = d_in[2];
    const void* tr_r = d_in[3];
    const void* Wenc_r = d_in[4];
    const void* benc_r = d_in[5];
    const void* Wm_r = d_in[6];
    const void* bm_r = d_in[7];
    const void* Wu_r = d_in[8];
    const void* bu_r = d_in[9];
    const int* e_r = (const int*)d_in[10];
    const int* cc_r = (const int*)d_in[11];

    char* w = (char*)d_ws;
    auto alloc = [&](size_t bytes) -> char* {
        char* p = w;
        w += (bytes + 63) & ~(size_t)63;
        return p;
    };
    bf16* xb0 = (bf16*)alloc((size_t)N_NODES * HD * 2);
    bf16* xb1 = (bf16*)alloc((size_t)N_NODES * HD * 2);
    bf16* mb = (bf16*)alloc((size_t)N_NODES * HD * 2);
    bf16* xin = (bf16*)alloc((size_t)N_NODES * 64 * 2);
    bf16* Wc = (bf16*)alloc(128 * 384 * 2);
    float* bc = (float*)alloc(128 * 4);
    bf16* Wet = (bf16*)alloc(128 * 64 * 2);
    float* bcenc = (float*)alloc(128 * 4);
    float* pooledf = (float*)alloc(NBC * HD * 4);
    bf16* pooled = (bf16*)alloc(NBC * HD * 2);
    int* deg = (int*)alloc(N_NODES * 4);
    int* rowptr = (int*)alloc((N_NODES + 1) * 4);
    int* cursor = (int*)alloc(N_NODES * 4);
    int* colx = (int*)alloc(N_EDGES * 4);
    int* ccount = (int*)alloc(NBC * 4);
    int* coff = (int*)alloc((NBC + 1) * 4);
    int* ccur = (int*)alloc(NBC * 4);
    int* cnodes = (int*)alloc(N_NODES * 4);
    int* flags = (int*)alloc(64);
    int* bsum = (int*)alloc(SCAN_B * 4);
    int* boff = (int*)alloc(SCAN_B * 4);
    int* n0list = (int*)alloc(MAXFIX * 4);
    int* n0cnt = (int*)alloc(64);
    bf16* trc = (bf16*)alloc(384 * 2);
    bf16* Wencc = (bf16*)alloc(6144 * 2);
    bf16* bencc = (bf16*)alloc(128 * 2);
    bf16* Wmc = (bf16*)alloc(32768 * 2);
    bf16* bmc = (bf16*)alloc(128 * 2);
    bf16* Wuc = (bf16*)alloc(49152 * 2);
    bf16* buc = (bf16*)alloc(128 * 2);
    int* ec = (int*)alloc(2 * N_EDGES * 4);
    int* ccc = (int*)alloc(N_NODES * 4);

    // dtype detection + canonical conversion (xin zeroed first for pad cols)
    k_detect<<<1, 64, 0, stream>>>((const unsigned short*)Wenc_r, e_r, flags);
    hipMemsetAsync(xin, 0, (size_t)N_NODES * 64 * 2, stream);
    k_cvt_all<<<C10, 256, 0, stream>>>(flags, cf_r, slf_r, z_r, tr_r, Wenc_r, benc_r,
                                       Wm_r, bm_r, Wu_r, bu_r,
                                       xin, trc, Wencc, bencc, Wmc, bmc, Wuc, buc);
    k_cvt_ints<<<B_E + 391, 256, 0, stream>>>(flags, e_r, cc_r, ec, ccc);

    // composed weights + MFMA encoder
    k_prep2<<<225, 256, 0, stream>>>(Wmc, Wuc, bmc, buc, Wencc, bencc, Wc, bc, Wet, bcenc);
    k_encoder_mfma<<<(N_NODES + 63) / 64, 256, 0, stream>>>(xin, Wet, bcenc, xb0);

    // CSR build
    hipMemsetAsync(deg, 0, (size_t)N_NODES * 4, stream);
    hipMemsetAsync(ccount, 0, (size_t)NBC * 4, stream);
    hipMemsetAsync(n0cnt, 0, 64, stream);
    k_count_edges<<<(N_EDGES + 255) / 256, 256, 0, stream>>>(ec, deg);
    k_count_nodes<<<(N_NODES + 255) / 256, 256, 0, stream>>>(ccc, ccount);
    k_scan_a<<<SCAN_B, 1024, 0, stream>>>(deg, rowptr, bsum);
    k_scan_b<<<1, 128, 0, stream>>>(bsum, boff, rowptr);
    k_scan_c<<<SCAN_B, 1024, 0, stream>>>(rowptr, cursor, boff);
    k_scan_clusters<<<1, 512, 0, stream>>>(ccount, coff, ccur);
    k_fill_edges<<<(N_EDGES + 255) / 256, 256, 0, stream>>>(ec, cursor, colx);
    k_fill_nodes<<<(N_NODES + 255) / 256, 256, 0, stream>>>(ccc, ccur, cnodes);
    k_list0<<<(N_NODES + 255) / 256, 256, 0, stream>>>(deg, n0list, n0cnt);

    bf16* xbufs[2] = {xb0, xb1};
    for (int layer = 0; layer < 3; layer++) {
        bf16* xbi = xbufs[layer & 1];
        bf16* xbo = xbufs[(layer + 1) & 1];
        int last = (layer == 2);
        hipMemsetAsync(pooledf, 0, (size_t)NBC * HD * 4, stream);
        k_aggregate<<<N_NODES / 4, 256, 0, stream>>>(xbi, rowptr, colx, mb);
        k_pool_partial<<<NBC * 4, 256, 0, stream>>>(xbi, coff, cnodes, pooledf);
        k_pool_final<<<NBC * HD / 256, 256, 0, stream>>>(pooledf, ccount, trc, pooled);
        k_fused2<<<GRID_F, 256, 0, stream>>>(xbi, mb, pooled, Wc, bc,
                                             ccc, deg, xbo, flags, d_out, last);
        k_fix<<<256, 128, 0, stream>>>(xbi, pooled, Wuc, buc, ccc,
                                       n0list, n0cnt, xbo, flags, d_out, last);
    }
}